// Round 12
// baseline (366.799 us; speedup 1.0000x reference)
//
#include <hip/hip_runtime.h>
#include <hip/hip_bf16.h>

#define N_NODES 50000
#define N_EDGES 1600000
#define IN_F 128
#define OUT_F 32
#define HEADS 4
#define NEG_SLOPE 0.2f
#define HO (HEADS * OUT_F)

#define PROJ_GRPS ((N_NODES + 255) / 256)      // 196 groups of 256 nodes
#define PROJ_BLOCKS (PROJ_GRPS * HEADS)        // 784
#define HIST_BLOCKS (N_EDGES / 256)            // 6250
#define FUSED_BLOCKS (PROJ_BLOCKS * 8 + (HIST_BLOCKS - (PROJ_BLOCKS * 8 - PROJ_BLOCKS)))
// proj occupies every 8th block among the first 6272; hist fills the rest.
#define GRID_BLOCKS (PROJ_BLOCKS + HIST_BLOCKS)   // 7034
#define SCAN_B ((N_NODES + 255) / 256)         // 196
#define AGG_BLOCKS 3125
#define AGG_WAVES (AGG_BLOCKS * 4)

__device__ __forceinline__ unsigned short bf16_bits(float f) {
    union { __hip_bfloat16 b; unsigned short u; } cv;
    cv.b = __float2bfloat16(f);
    return cv.u;
}
__device__ __forceinline__ float bf16u(unsigned short u) {
    return __uint_as_float((unsigned)u << 16);
}

// K1 fused: every 8th block (among first 6272) = projection, rest = histogram.
// Projection: lane = node; x chunk in VGPRs; W (one head, 16 KB f32) in LDS,
// read wave-uniform (broadcast, conflict-free). No x staging, no big LDS.
__global__ __launch_bounds__(256) void k_proj_hist(
    const float* __restrict__ x, const float* __restrict__ W,
    const float* __restrict__ a_src, const float* __restrict__ a_dst,
    const int* __restrict__ ei,
    int* __restrict__ counts, int* __restrict__ rank,
    unsigned* __restrict__ h32, float* __restrict__ attn_s4,
    float* __restrict__ attn_d4)
{
    __shared__ float4 Wl[1024];                 // [k=128][o4=8], 16 KB
    const int b = blockIdx.x;
    const int tid = threadIdx.x;
    const bool isProj = (b < PROJ_BLOCKS * 8) && ((b & 7) == 0);

    if (!isProj) {
        // ---- histogram: 256 edges per block ----
        const int hb = (b < PROJ_BLOCKS * 8) ? (b - ((b + 7) >> 3))
                                             : (b - PROJ_BLOCKS);
        const int e = hb * 256 + tid;
        rank[e] = atomicAdd(&counts[ei[N_EDGES + e]], 1);
        return;
    }

    const int pid  = b >> 3;
    const int head = pid & 3;
    const int grp  = pid >> 2;                  // 0..195
    const int node = grp * 256 + tid;

    {   // stage one head's W slice [128][32] f32
        const float4* W4 = (const float4*)W + (size_t)head * 1024;
        Wl[tid]       = W4[tid];
        Wl[tid + 256] = W4[tid + 256];
        Wl[tid + 512] = W4[tid + 512];
        Wl[tid + 768] = W4[tid + 768];
    }
    __syncthreads();
    if (node >= N_NODES) return;

    const float4* xp = (const float4*)x + (size_t)node * 32;
    float acc[32];
    #pragma unroll
    for (int o = 0; o < 32; ++o) acc[o] = 0.f;

    for (int kc = 0; kc < 4; ++kc) {            // 32 k per chunk
        float4 xq[8];
        #pragma unroll
        for (int q = 0; q < 8; ++q) xq[q] = xp[kc * 8 + q];
        #pragma unroll
        for (int q = 0; q < 8; ++q) {
            const float xk[4] = {xq[q].x, xq[q].y, xq[q].z, xq[q].w};
            #pragma unroll
            for (int j = 0; j < 4; ++j) {
                const int k = kc * 32 + q * 4 + j;
                const float xv = xk[j];
                #pragma unroll
                for (int o4 = 0; o4 < 8; ++o4) {
                    const float4 wv = Wl[k * 8 + o4];   // wave-uniform
                    acc[o4 * 4 + 0] = fmaf(xv, wv.x, acc[o4 * 4 + 0]);
                    acc[o4 * 4 + 1] = fmaf(xv, wv.y, acc[o4 * 4 + 1]);
                    acc[o4 * 4 + 2] = fmaf(xv, wv.z, acc[o4 * 4 + 2]);
                    acc[o4 * 4 + 3] = fmaf(xv, wv.w, acc[o4 * 4 + 3]);
                }
            }
        }
    }

    // attn dots (a vectors are tiny, L2-resident; wave-uniform loads)
    float ts = 0.f, td = 0.f;
    #pragma unroll
    for (int o = 0; o < 32; ++o) {
        ts = fmaf(acc[o], a_src[head * OUT_F + o], ts);
        td = fmaf(acc[o], a_dst[head * OUT_F + o], td);
    }
    attn_s4[node * HEADS + head] = ts;
    attn_d4[node * HEADS + head] = td;

    // pack h to bf16 and store 4x uint4
    unsigned hp[16];
    #pragma unroll
    for (int i = 0; i < 16; ++i)
        hp[i] = (unsigned)bf16_bits(acc[2 * i]) |
                ((unsigned)bf16_bits(acc[2 * i + 1]) << 16);
    uint4* dstp = (uint4*)(h32 + (size_t)node * 64 + head * 16);
    #pragma unroll
    for (int q = 0; q < 4; ++q)
        dstp[q] = make_uint4(hp[4 * q], hp[4 * q + 1], hp[4 * q + 2], hp[4 * q + 3]);
}

// K2a: per-block partial sums of counts
__global__ __launch_bounds__(256) void k_scan_part(
    const int* __restrict__ counts, int* __restrict__ bsum)
{
    const int i = blockIdx.x * 256 + threadIdx.x;
    int v = (i < N_NODES) ? counts[i] : 0;
    #pragma unroll
    for (int s = 32; s >= 1; s >>= 1) v += __shfl_xor(v, s);
    __shared__ int w[4];
    if ((threadIdx.x & 63) == 0) w[threadIdx.x >> 6] = v;
    __syncthreads();
    if (threadIdx.x == 0)
        bsum[blockIdx.x] = (w[0] + w[1]) + (w[2] + w[3]);
}

// K2b: exclusive scan of 196 block sums
__global__ __launch_bounds__(256) void k_scan_base(
    const int* __restrict__ bsum, int* __restrict__ bbase)
{
    __shared__ int arr[256];
    const int t = threadIdx.x;
    arr[t] = (t < SCAN_B) ? bsum[t] : 0;
    __syncthreads();
    for (int d = 1; d < 256; d <<= 1) {
        const int v = (t >= d) ? arr[t - d] : 0;
        __syncthreads();
        arr[t] += v;
        __syncthreads();
    }
    bbase[t] = (t == 0) ? 0 : arr[t - 1];
}

// K2c: apply: offsets[i] = bbase[b] + local exclusive scan
__global__ __launch_bounds__(256) void k_scan_apply(
    const int* __restrict__ counts, const int* __restrict__ bbase,
    int* __restrict__ offsets)
{
    __shared__ int arr[256];
    const int t = threadIdx.x;
    const int i = blockIdx.x * 256 + t;
    const int c = (i < N_NODES) ? counts[i] : 0;
    arr[t] = c;
    __syncthreads();
    for (int d = 1; d < 256; d <<= 1) {
        const int v = (t >= d) ? arr[t - d] : 0;
        __syncthreads();
        arr[t] += v;
        __syncthreads();
    }
    const int incl = arr[t];
    const int base = bbase[blockIdx.x];
    if (i < N_NODES) offsets[i] = base + incl - c;
    if (i == N_NODES - 1) offsets[N_NODES] = base + incl;
}

// K3: atomic-free scatter of per-edge records, pre-exponentiated, bf16x4.
__global__ __launch_bounds__(256) void k_edges(
    const int* __restrict__ ei, const float* __restrict__ ew,
    const int* __restrict__ rank, const int* __restrict__ offsets,
    const float* __restrict__ attn_s4, const float* __restrict__ attn_d4,
    int* __restrict__ srcs, ushort4* __restrict__ pexp8)
{
    const int e = blockIdx.x * 256 + threadIdx.x;   // grid covers E exactly
    const int src = ei[e];
    const int dst = ei[N_EDGES + e];
    const float w = ew[e];
    const int pos = offsets[dst] + rank[e];
    const float4 as = ((const float4*)attn_s4)[src];
    const float4 ad = ((const float4*)attn_d4)[dst];
    float l;
    ushort4 p;
    l = as.x + ad.x; l = ((l >= 0.f) ? l : NEG_SLOPE * l) * w; p.x = bf16_bits(__expf(l));
    l = as.y + ad.y; l = ((l >= 0.f) ? l : NEG_SLOPE * l) * w; p.y = bf16_bits(__expf(l));
    l = as.z + ad.z; l = ((l >= 0.f) ? l : NEG_SLOPE * l) * w; p.z = bf16_bits(__expf(l));
    l = as.w + ad.w; l = ((l >= 0.f) ? l : NEG_SLOPE * l) * w; p.w = bf16_bits(__expf(l));
    srcs[pos] = src;
    pexp8[pos] = p;
}

// K4: per-dst gather-aggregate. One wave per dst; each thread owns 2 adjacent
// cols (one u32 = 2 bf16), 8-edge unroll, independent chains. Every lane
// accumulates the FULL denominator -> no cross-lane reduction.
__global__ __launch_bounds__(256) void k_aggregate(
    const int* __restrict__ srcs, const unsigned short* __restrict__ pexp,
    const int* __restrict__ offsets, const unsigned* __restrict__ h32,
    float* __restrict__ out)
{
    const int l = threadIdx.x & 63;                 // lane within wave
    const int head = l >> 4;                        // head of cols 2l,2l+1
    const int wid = blockIdx.x * 4 + (threadIdx.x >> 6);
    const unsigned* hp = h32 + l;                   // u32 col-pair l

    for (int dst = wid; dst < N_NODES; dst += AGG_WAVES) {
        const int beg = offsets[dst];
        const int end = offsets[dst + 1];
        float den = 0.f;
        float a0 = 0.f, a1 = 0.f, a2 = 0.f, a3 = 0.f;   // even cols
        float b0 = 0.f, b1 = 0.f, b2 = 0.f, b3 = 0.f;   // odd cols
        int e = beg;
        for (; e + 8 <= end; e += 8) {
            const int s0 = srcs[e + 0], s1 = srcs[e + 1];
            const int s2 = srcs[e + 2], s3 = srcs[e + 3];
            const int s4 = srcs[e + 4], s5 = srcs[e + 5];
            const int s6 = srcs[e + 6], s7 = srcs[e + 7];
            const float p0 = bf16u(pexp[(size_t)(e + 0) * 4 + head]);
            const float p1 = bf16u(pexp[(size_t)(e + 1) * 4 + head]);
            const float p2 = bf16u(pexp[(size_t)(e + 2) * 4 + head]);
            const float p3 = bf16u(pexp[(size_t)(e + 3) * 4 + head]);
            const float p4 = bf16u(pexp[(size_t)(e + 4) * 4 + head]);
            const float p5 = bf16u(pexp[(size_t)(e + 5) * 4 + head]);
            const float p6 = bf16u(pexp[(size_t)(e + 6) * 4 + head]);
            const float p7 = bf16u(pexp[(size_t)(e + 7) * 4 + head]);
            const unsigned h0 = hp[(size_t)s0 * 64];
            const unsigned h1 = hp[(size_t)s1 * 64];
            const unsigned h2 = hp[(size_t)s2 * 64];
            const unsigned h3 = hp[(size_t)s3 * 64];
            const unsigned h4 = hp[(size_t)s4 * 64];
            const unsigned h5 = hp[(size_t)s5 * 64];
            const unsigned h6 = hp[(size_t)s6 * 64];
            const unsigned h7 = hp[(size_t)s7 * 64];
            a0 = fmaf(p0, __uint_as_float(h0 << 16), a0);
            b0 = fmaf(p0, __uint_as_float(h0 & 0xffff0000u), b0);
            a1 = fmaf(p1, __uint_as_float(h1 << 16), a1);
            b1 = fmaf(p1, __uint_as_float(h1 & 0xffff0000u), b1);
            a2 = fmaf(p2, __uint_as_float(h2 << 16), a2);
            b2 = fmaf(p2, __uint_as_float(h2 & 0xffff0000u), b2);
            a3 = fmaf(p3, __uint_as_float(h3 << 16), a3);
            b3 = fmaf(p3, __uint_as_float(h3 & 0xffff0000u), b3);
            a0 = fmaf(p4, __uint_as_float(h4 << 16), a0);
            b0 = fmaf(p4, __uint_as_float(h4 & 0xffff0000u), b0);
            a1 = fmaf(p5, __uint_as_float(h5 << 16), a1);
            b1 = fmaf(p5, __uint_as_float(h5 & 0xffff0000u), b1);
            a2 = fmaf(p6, __uint_as_float(h6 << 16), a2);
            b2 = fmaf(p6, __uint_as_float(h6 & 0xffff0000u), b2);
            a3 = fmaf(p7, __uint_as_float(h7 << 16), a3);
            b3 = fmaf(p7, __uint_as_float(h7 & 0xffff0000u), b3);
            den += ((p0 + p1) + (p2 + p3)) + ((p4 + p5) + (p6 + p7));
        }
        for (; e < end; ++e) {
            const float p = bf16u(pexp[(size_t)e * 4 + head]);
            const unsigned h = hp[(size_t)srcs[e] * 64];
            a0 = fmaf(p, __uint_as_float(h << 16), a0);
            b0 = fmaf(p, __uint_as_float(h & 0xffff0000u), b0);
            den += p;
        }
        const float inv = 1.f / (den + 1e-10f);
        float2 o;
        o.x = ((a0 + a1) + (a2 + a3)) * inv;
        o.y = ((b0 + b1) + (b2 + b3)) * inv;
        ((float2*)out)[(size_t)dst * 64 + l] = o;
    }
}

extern "C" void kernel_launch(void* const* d_in, const int* in_sizes, int n_in,
                              void* d_out, int out_size, void* d_ws, size_t ws_size,
                              hipStream_t stream) {
    const float* x   = (const float*)d_in[0];
    const int*   ei  = (const int*)d_in[1];
    const float* ew  = (const float*)d_in[2];
    const float* W   = (const float*)d_in[3];
    const float* a_s = (const float*)d_in[4];
    const float* a_d = (const float*)d_in[5];
    float* out = (float*)d_out;

    unsigned* h32    = (unsigned*)d_ws;                           // 12.8 MB
    float*   attn_s4 = (float*)(h32 + (size_t)N_NODES * 64);      // 800 KB
    float*   attn_d4 = attn_s4 + (size_t)N_NODES * HEADS;         // 800 KB
    ushort4* pexp8   = (ushort4*)(attn_d4 + (size_t)N_NODES * HEADS); // 12.8 MB
    int*     srcs    = (int*)(pexp8 + N_EDGES);                   // 6.4 MB
    int*     rank    = srcs + N_EDGES;                            // 6.4 MB
    int*     counts  = rank + N_EDGES;                            // 200 KB
    int*     offsets = counts + N_NODES;                          // 200 KB
    int*     bsum    = offsets + N_NODES + 1;                     // 196
    int*     bbase   = bsum + 256;                                // 256

    hipMemsetAsync(counts, 0, N_NODES * sizeof(int), stream);

    k_proj_hist<<<GRID_BLOCKS, 256, 0, stream>>>(
        x, W, a_s, a_d, ei, counts, rank, h32, attn_s4, attn_d4);
    k_scan_part <<<SCAN_B, 256, 0, stream>>>(counts, bsum);
    k_scan_base <<<1, 256, 0, stream>>>(bsum, bbase);
    k_scan_apply<<<SCAN_B, 256, 0, stream>>>(counts, bbase, offsets);
    k_edges<<<N_EDGES / 256, 256, 0, stream>>>(
        ei, ew, rank, offsets, attn_s4, attn_d4, srcs, pexp8);
    k_aggregate<<<AGG_BLOCKS, 256, 0, stream>>>(
        srcs, (const unsigned short*)pexp8, offsets, h32, out);
}

// Round 13
// 228.248 us; speedup vs baseline: 1.6070x; 1.6070x over previous
//
#include <hip/hip_runtime.h>
#include <hip/hip_bf16.h>

#define N_NODES 50000
#define N_EDGES 1600000
#define IN_F 128
#define OUT_F 32
#define HEADS 4
#define NEG_SLOPE 0.2f
#define HO (HEADS * OUT_F)

#define CVT_BLOCKS 3125                        // x -> bf16, 2048 elems/block
#define HIST_BLOCKS (N_EDGES / 256)            // 6250
#define PROJ_BLOCKS ((N_NODES + 63) / 64)      // 782, 64 nodes/block
#define ATTN_BLOCKS ((N_NODES + 31) / 32)      // 1563
#define SCAN_B ((N_NODES + 255) / 256)         // 196
#define AGG_BLOCKS 3125
#define AGG_WAVES (AGG_BLOCKS * 4)

#define WPITCH 136                             // bf16 pitch (17 x b128)

typedef __attribute__((ext_vector_type(8))) short bf16x8;
typedef __attribute__((ext_vector_type(4))) float f32x4;

__device__ __forceinline__ unsigned short bf16_bits(float f) {
    union { __hip_bfloat16 b; unsigned short u; } cv;
    cv.b = __float2bfloat16(f);
    return cv.u;
}
__device__ __forceinline__ float bf16u(unsigned short u) {
    return __uint_as_float((unsigned)u << 16);
}

// K0: build Wtg[col][k] bf16, padded pitch 136: Wtg[32h+o][i] = W[h][i][o]
__global__ __launch_bounds__(256) void k_prep(
    const float* __restrict__ W, unsigned short* __restrict__ Wtg)
{
    const int t = threadIdx.x;
    #pragma unroll
    for (int i = 0; i < 64; ++i) {
        const int idx = t + i * 256;           // 16384 f32
        const int h = idx >> 12;
        const int k = (idx >> 5) & 127;
        const int o = idx & 31;
        Wtg[(size_t)(h * 32 + o) * WPITCH + k] = bf16_bits(W[idx]);
    }
}

// K1 fused: blocks [0,3125) convert x->bf16; rest = histogram + rank.
__global__ __launch_bounds__(256) void k_cvt_hist(
    const float* __restrict__ x, unsigned short* __restrict__ xb,
    const int* __restrict__ ei, int* __restrict__ counts,
    int* __restrict__ rank)
{
    const int b = blockIdx.x;
    const int t = threadIdx.x;
    if (b < CVT_BLOCKS) {
        const size_t base = ((size_t)b * 256 + t) * 8;
        const float4 v0 = *(const float4*)(x + base);
        const float4 v1 = *(const float4*)(x + base + 4);
        ushort4 o0, o1;
        o0.x = bf16_bits(v0.x); o0.y = bf16_bits(v0.y);
        o0.z = bf16_bits(v0.z); o0.w = bf16_bits(v0.w);
        o1.x = bf16_bits(v1.x); o1.y = bf16_bits(v1.y);
        o1.z = bf16_bits(v1.z); o1.w = bf16_bits(v1.w);
        *(ushort4*)(xb + base) = o0;
        *(ushort4*)(xb + base + 4) = o1;
        return;
    }
    const int e = (b - CVT_BLOCKS) * 256 + t;
    rank[e] = atomicAdd(&counts[ei[N_EDGES + e]], 1);
}

// K2: MFMA projection. Block = 64 nodes x 128 cols, K=128.
// LDS: xb tile [64][136] bf16 + Wt [128][136] bf16 (52 KB).
// Wave w owns m-tile w (16 nodes) x 8 col-tiles; 32 mfma/wave.
__global__ __launch_bounds__(256, 2) void k_proj(
    const unsigned short* __restrict__ xb, const unsigned short* __restrict__ Wtg,
    unsigned short* __restrict__ h_u16)
{
    __shared__ unsigned short xls[64 * WPITCH];    // 17408 B
    __shared__ unsigned short wls[128 * WPITCH];   // 34816 B
    const int t = threadIdx.x;
    const int base = blockIdx.x * 64;

    {   // stage Wt (flat copy, already padded): 2176 uint4
        const uint4* src = (const uint4*)Wtg;
        uint4* dst = (uint4*)wls;
        for (int i = t; i < 2176; i += 256) dst[i] = src[i];
    }
    {   // stage x tile: 64 rows x 16 uint4, dest pitch 17
        uint4* dst = (uint4*)xls;
        #pragma unroll
        for (int i = 0; i < 4; ++i) {
            const int idx = t + i * 256;           // 0..1023
            const int row = idx >> 4;
            const int c = idx & 15;
            const int node = base + row;
            uint4 v = make_uint4(0u, 0u, 0u, 0u);
            if (node < N_NODES)
                v = ((const uint4*)xb)[(size_t)node * 16 + c];
            dst[row * 17 + c] = v;
        }
    }
    __syncthreads();

    const int w = t >> 6;                          // m-tile 0..3
    const int lane = t & 63;
    const int lr = lane & 15;                      // A-row / B-col
    const int lq = lane >> 4;                      // k-quadrant

    const unsigned short* ap = &xls[(w * 16 + lr) * WPITCH + lq * 8];
    const unsigned short* bp = &wls[lr * WPITCH + lq * 8];

    f32x4 acc0 = {0,0,0,0}, acc1 = {0,0,0,0}, acc2 = {0,0,0,0}, acc3 = {0,0,0,0};
    f32x4 acc4 = {0,0,0,0}, acc5 = {0,0,0,0}, acc6 = {0,0,0,0}, acc7 = {0,0,0,0};
    #pragma unroll
    for (int ks = 0; ks < 4; ++ks) {
        const bf16x8 a = *(const bf16x8*)(ap + ks * 32);
        const bf16x8 b0 = *(const bf16x8*)(bp + 0 * 16 * WPITCH + ks * 32);
        const bf16x8 b1 = *(const bf16x8*)(bp + 1 * 16 * WPITCH + ks * 32);
        const bf16x8 b2 = *(const bf16x8*)(bp + 2 * 16 * WPITCH + ks * 32);
        const bf16x8 b3 = *(const bf16x8*)(bp + 3 * 16 * WPITCH + ks * 32);
        const bf16x8 b4 = *(const bf16x8*)(bp + 4 * 16 * WPITCH + ks * 32);
        const bf16x8 b5 = *(const bf16x8*)(bp + 5 * 16 * WPITCH + ks * 32);
        const bf16x8 b6 = *(const bf16x8*)(bp + 6 * 16 * WPITCH + ks * 32);
        const bf16x8 b7 = *(const bf16x8*)(bp + 7 * 16 * WPITCH + ks * 32);
        acc0 = __builtin_amdgcn_mfma_f32_16x16x32_bf16(a, b0, acc0, 0, 0, 0);
        acc1 = __builtin_amdgcn_mfma_f32_16x16x32_bf16(a, b1, acc1, 0, 0, 0);
        acc2 = __builtin_amdgcn_mfma_f32_16x16x32_bf16(a, b2, acc2, 0, 0, 0);
        acc3 = __builtin_amdgcn_mfma_f32_16x16x32_bf16(a, b3, acc3, 0, 0, 0);
        acc4 = __builtin_amdgcn_mfma_f32_16x16x32_bf16(a, b4, acc4, 0, 0, 0);
        acc5 = __builtin_amdgcn_mfma_f32_16x16x32_bf16(a, b5, acc5, 0, 0, 0);
        acc6 = __builtin_amdgcn_mfma_f32_16x16x32_bf16(a, b6, acc6, 0, 0, 0);
        acc7 = __builtin_amdgcn_mfma_f32_16x16x32_bf16(a, b7, acc7, 0, 0, 0);
    }
    // D: node = base + 16w + lq*4 + r, col = ct*16 + lr
    const int nodeq = base + w * 16 + lq * 4;
    #pragma unroll
    for (int r = 0; r < 4; ++r) {
        const int node = nodeq + r;
        if (node >= N_NODES) continue;
        unsigned short* hrow = h_u16 + (size_t)node * 128 + lr;
        hrow[0 * 16] = bf16_bits(acc0[r]);
        hrow[1 * 16] = bf16_bits(acc1[r]);
        hrow[2 * 16] = bf16_bits(acc2[r]);
        hrow[3 * 16] = bf16_bits(acc3[r]);
        hrow[4 * 16] = bf16_bits(acc4[r]);
        hrow[5 * 16] = bf16_bits(acc5[r]);
        hrow[6 * 16] = bf16_bits(acc6[r]);
        hrow[7 * 16] = bf16_bits(acc7[r]);
    }
}

// K3: attn dots from bf16 h. Block = 32 nodes x 8 col-groups of 16.
__global__ __launch_bounds__(256) void k_attn(
    const unsigned* __restrict__ h32, const float* __restrict__ a_src,
    const float* __restrict__ a_dst, float* __restrict__ attn_s4,
    float* __restrict__ attn_d4)
{
    __shared__ float asl[128], adl[128];
    const int t = threadIdx.x;
    if (t < 128) { asl[t] = a_src[t]; adl[t] = a_dst[t]; }
    __syncthreads();
    const int nl = t >> 3;                         // local node
    const int j = t & 7;                           // 16-col group
    const int node = blockIdx.x * 32 + nl;
    if (node >= N_NODES) return;
    const uint4* hp = (const uint4*)(h32 + (size_t)node * 64 + j * 8);
    const uint4 q0 = hp[0], q1 = hp[1];
    const unsigned hv[8] = {q0.x, q0.y, q0.z, q0.w, q1.x, q1.y, q1.z, q1.w};
    const int c0 = j * 16;
    float ts = 0.f, td = 0.f;
    #pragma unroll
    for (int i = 0; i < 8; ++i) {
        const float h0 = __uint_as_float(hv[i] << 16);
        const float h1 = __uint_as_float(hv[i] & 0xffff0000u);
        const int c = c0 + 2 * i;
        ts = fmaf(h0, asl[c], ts); ts = fmaf(h1, asl[c + 1], ts);
        td = fmaf(h0, adl[c], td); td = fmaf(h1, adl[c + 1], td);
    }
    ts += __shfl_xor(ts, 1);
    td += __shfl_xor(td, 1);
    if ((j & 1) == 0) {
        attn_s4[node * HEADS + (j >> 1)] = ts;
        attn_d4[node * HEADS + (j >> 1)] = td;
    }
}

// K4a/b/c: scan of counts -> offsets
__global__ __launch_bounds__(256) void k_scan_part(
    const int* __restrict__ counts, int* __restrict__ bsum)
{
    const int i = blockIdx.x * 256 + threadIdx.x;
    int v = (i < N_NODES) ? counts[i] : 0;
    #pragma unroll
    for (int s = 32; s >= 1; s >>= 1) v += __shfl_xor(v, s);
    __shared__ int w[4];
    if ((threadIdx.x & 63) == 0) w[threadIdx.x >> 6] = v;
    __syncthreads();
    if (threadIdx.x == 0) bsum[blockIdx.x] = (w[0] + w[1]) + (w[2] + w[3]);
}
__global__ __launch_bounds__(256) void k_scan_base(
    const int* __restrict__ bsum, int* __restrict__ bbase)
{
    __shared__ int arr[256];
    const int t = threadIdx.x;
    arr[t] = (t < SCAN_B) ? bsum[t] : 0;
    __syncthreads();
    for (int d = 1; d < 256; d <<= 1) {
        const int v = (t >= d) ? arr[t - d] : 0;
        __syncthreads();
        arr[t] += v;
        __syncthreads();
    }
    bbase[t] = (t == 0) ? 0 : arr[t - 1];
}
__global__ __launch_bounds__(256) void k_scan_apply(
    const int* __restrict__ counts, const int* __restrict__ bbase,
    int* __restrict__ offsets)
{
    __shared__ int arr[256];
    const int t = threadIdx.x;
    const int i = blockIdx.x * 256 + t;
    const int c = (i < N_NODES) ? counts[i] : 0;
    arr[t] = c;
    __syncthreads();
    for (int d = 1; d < 256; d <<= 1) {
        const int v = (t >= d) ? arr[t - d] : 0;
        __syncthreads();
        arr[t] += v;
        __syncthreads();
    }
    const int incl = arr[t];
    const int base = bbase[blockIdx.x];
    if (i < N_NODES) offsets[i] = base + incl - c;
    if (i == N_NODES - 1) offsets[N_NODES] = base + incl;
}

// K5: atomic-free scatter of per-edge records, pre-exponentiated, bf16x4.
__global__ __launch_bounds__(256) void k_edges(
    const int* __restrict__ ei, const float* __restrict__ ew,
    const int* __restrict__ rank, const int* __restrict__ offsets,
    const float* __restrict__ attn_s4, const float* __restrict__ attn_d4,
    int* __restrict__ srcs, ushort4* __restrict__ pexp8)
{
    const int e = blockIdx.x * 256 + threadIdx.x;
    const int src = ei[e];
    const int dst = ei[N_EDGES + e];
    const float w = ew[e];
    const int pos = offsets[dst] + rank[e];
    const float4 as = ((const float4*)attn_s4)[src];
    const float4 ad = ((const float4*)attn_d4)[dst];
    float l;
    ushort4 p;
    l = as.x + ad.x; l = ((l >= 0.f) ? l : NEG_SLOPE * l) * w; p.x = bf16_bits(__expf(l));
    l = as.y + ad.y; l = ((l >= 0.f) ? l : NEG_SLOPE * l) * w; p.y = bf16_bits(__expf(l));
    l = as.z + ad.z; l = ((l >= 0.f) ? l : NEG_SLOPE * l) * w; p.z = bf16_bits(__expf(l));
    l = as.w + ad.w; l = ((l >= 0.f) ? l : NEG_SLOPE * l) * w; p.w = bf16_bits(__expf(l));
    srcs[pos] = src;
    pexp8[pos] = p;
}

// K6: per-dst gather-aggregate (round-11, known good). Every lane holds the
// full denominator -> no cross-lane reduction.
__global__ __launch_bounds__(256) void k_aggregate(
    const int* __restrict__ srcs, const unsigned short* __restrict__ pexp,
    const int* __restrict__ offsets, const unsigned* __restrict__ h32,
    float* __restrict__ out)
{
    const int l = threadIdx.x & 63;
    const int head = l >> 4;
    const int wid = blockIdx.x * 4 + (threadIdx.x >> 6);
    const unsigned* hp = h32 + l;

    for (int dst = wid; dst < N_NODES; dst += AGG_WAVES) {
        const int beg = offsets[dst];
        const int end = offsets[dst + 1];
        float den = 0.f;
        float a0 = 0.f, a1 = 0.f, a2 = 0.f, a3 = 0.f;
        float b0 = 0.f, b1 = 0.f, b2 = 0.f, b3 = 0.f;
        int e = beg;
        for (; e + 8 <= end; e += 8) {
            const int s0 = srcs[e + 0], s1 = srcs[e + 1];
            const int s2 = srcs[e + 2], s3 = srcs[e + 3];
            const int s4 = srcs[e + 4], s5 = srcs[e + 5];
            const int s6 = srcs[e + 6], s7 = srcs[e + 7];
            const float p0 = bf16u(pexp[(size_t)(e + 0) * 4 + head]);
            const float p1 = bf16u(pexp[(size_t)(e + 1) * 4 + head]);
            const float p2 = bf16u(pexp[(size_t)(e + 2) * 4 + head]);
            const float p3 = bf16u(pexp[(size_t)(e + 3) * 4 + head]);
            const float p4 = bf16u(pexp[(size_t)(e + 4) * 4 + head]);
            const float p5 = bf16u(pexp[(size_t)(e + 5) * 4 + head]);
            const float p6 = bf16u(pexp[(size_t)(e + 6) * 4 + head]);
            const float p7 = bf16u(pexp[(size_t)(e + 7) * 4 + head]);
            const unsigned h0 = hp[(size_t)s0 * 64];
            const unsigned h1 = hp[(size_t)s1 * 64];
            const unsigned h2 = hp[(size_t)s2 * 64];
            const unsigned h3 = hp[(size_t)s3 * 64];
            const unsigned h4 = hp[(size_t)s4 * 64];
            const unsigned h5 = hp[(size_t)s5 * 64];
            const unsigned h6 = hp[(size_t)s6 * 64];
            const unsigned h7 = hp[(size_t)s7 * 64];
            a0 = fmaf(p0, __uint_as_float(h0 << 16), a0);
            b0 = fmaf(p0, __uint_as_float(h0 & 0xffff0000u), b0);
            a1 = fmaf(p1, __uint_as_float(h1 << 16), a1);
            b1 = fmaf(p1, __uint_as_float(h1 & 0xffff0000u), b1);
            a2 = fmaf(p2, __uint_as_float(h2 << 16), a2);
            b2 = fmaf(p2, __uint_as_float(h2 & 0xffff0000u), b2);
            a3 = fmaf(p3, __uint_as_float(h3 << 16), a3);
            b3 = fmaf(p3, __uint_as_float(h3 & 0xffff0000u), b3);
            a0 = fmaf(p4, __uint_as_float(h4 << 16), a0);
            b0 = fmaf(p4, __uint_as_float(h4 & 0xffff0000u), b0);
            a1 = fmaf(p5, __uint_as_float(h5 << 16), a1);
            b1 = fmaf(p5, __uint_as_float(h5 & 0xffff0000u), b1);
            a2 = fmaf(p6, __uint_as_float(h6 << 16), a2);
            b2 = fmaf(p6, __uint_as_float(h6 & 0xffff0000u), b2);
            a3 = fmaf(p7, __uint_as_float(h7 << 16), a3);
            b3 = fmaf(p7, __uint_as_float(h7 & 0xffff0000u), b3);
            den += ((p0 + p1) + (p2 + p3)) + ((p4 + p5) + (p6 + p7));
        }
        for (; e < end; ++e) {
            const float p = bf16u(pexp[(size_t)e * 4 + head]);
            const unsigned h = hp[(size_t)srcs[e] * 64];
            a0 = fmaf(p, __uint_as_float(h << 16), a0);
            b0 = fmaf(p, __uint_as_float(h & 0xffff0000u), b0);
            den += p;
        }
        const float inv = 1.f / (den + 1e-10f);
        float2 o;
        o.x = ((a0 + a1) + (a2 + a3)) * inv;
        o.y = ((b0 + b1) + (b2 + b3)) * inv;
        ((float2*)out)[(size_t)dst * 64 + l] = o;
    }
}

extern "C" void kernel_launch(void* const* d_in, const int* in_sizes, int n_in,
                              void* d_out, int out_size, void* d_ws, size_t ws_size,
                              hipStream_t stream) {
    const float* x   = (const float*)d_in[0];
    const int*   ei  = (const int*)d_in[1];
    const float* ew  = (const float*)d_in[2];
    const float* W   = (const float*)d_in[3];
    const float* a_s = (const float*)d_in[4];
    const float* a_d = (const float*)d_in[5];
    float* out = (float*)d_out;

    unsigned* h32        = (unsigned*)d_ws;                          // 12.8 MB
    float*    attn_s4    = (float*)(h32 + (size_t)N_NODES * 64);     // 800 KB
    float*    attn_d4    = attn_s4 + (size_t)N_NODES * HEADS;        // 800 KB
    ushort4*  pexp8      = (ushort4*)(attn_d4 + (size_t)N_NODES * HEADS); // 12.8 MB
    unsigned short* xb   = (unsigned short*)(pexp8 + N_EDGES);       // 12.8 MB
    unsigned short* Wtg  = xb + (size_t)N_NODES * 128;               // 34.8 KB
    int*      srcs       = (int*)(Wtg + 128 * WPITCH);               // 6.4 MB
    int*      rank       = srcs + N_EDGES;                           // 6.4 MB
    int*      counts     = rank + N_EDGES;                           // 200 KB
    int*      offsets    = counts + N_NODES;                         // 200 KB
    int*      bsum       = offsets + N_NODES + 1;
    int*      bbase      = bsum + 256;

    hipMemsetAsync(counts, 0, N_NODES * sizeof(int), stream);

    k_prep<<<1, 256, 0, stream>>>(W, Wtg);
    k_cvt_hist<<<CVT_BLOCKS + HIST_BLOCKS, 256, 0, stream>>>(
        x, xb, ei, counts, rank);
    k_proj<<<PROJ_BLOCKS, 256, 0, stream>>>(xb, Wtg, (unsigned short*)h32);
    k_attn<<<ATTN_BLOCKS, 256, 0, stream>>>(h32, a_s, a_d, attn_s4, attn_d4);
    k_scan_part <<<SCAN_B, 256, 0, stream>>>(counts, bsum);
    k_scan_base <<<1, 256, 0, stream>>>(bsum, bbase);
    k_scan_apply<<<SCAN_B, 256, 0, stream>>>(counts, bbase, offsets);
    k_edges<<<N_EDGES / 256, 256, 0, stream>>>(
        ei, ew, rank, offsets, attn_s4, attn_d4, srcs, pexp8);
    k_aggregate<<<AGG_BLOCKS, 256, 0, stream>>>(
        srcs, (const unsigned short*)pexp8, offsets, h32, out);
}

// Round 14
// 215.755 us; speedup vs baseline: 1.7001x; 1.0579x over previous
//
#include <hip/hip_runtime.h>
#include <hip/hip_bf16.h>
#include <hip/hip_fp16.h>

#define N_NODES 50000
#define N_EDGES 1600000
#define IN_F 128
#define OUT_F 32
#define HEADS 4
#define NEG_SLOPE 0.2f
#define HO (HEADS * OUT_F)

#define CVT_BLOCKS 3125                        // x -> bf16, 2048 elems/block
#define HIST_BLOCKS (N_EDGES / 256)            // 6250
#define PROJ_BLOCKS ((N_NODES + 63) / 64)      // 782, 64 nodes/block
#define SCAN_B ((N_NODES + 255) / 256)         // 196
#define AGG_BLOCKS 3125
#define AGG_WAVES (AGG_BLOCKS * 4)

#define WPITCH 136                             // bf16 pitch (17 x b128)

typedef __attribute__((ext_vector_type(8))) short bf16x8;
typedef __attribute__((ext_vector_type(4))) float f32x4;

__device__ __forceinline__ unsigned short bf16_bits(float f) {
    union { __hip_bfloat16 b; unsigned short u; } cv;
    cv.b = __float2bfloat16(f);
    return cv.u;
}
__device__ __forceinline__ unsigned short f16_bits(float f) {
    union { __half h; unsigned short u; } cv;
    cv.h = __float2half(f);
    return cv.u;
}
__device__ __forceinline__ float f16u(unsigned short u) {
    union { unsigned short x; __half h; } cv;
    cv.x = u;
    return __half2float(cv.h);
}

// K1 fused: blocks [0,3125) convert x->bf16; next 6250 = histogram + rank;
// last block transposes W -> Wtg[col][k] bf16 (pitch 136).
__global__ __launch_bounds__(256) void k_front(
    const float* __restrict__ x, unsigned short* __restrict__ xb,
    const int* __restrict__ ei, int* __restrict__ counts,
    int* __restrict__ rank, const float* __restrict__ W,
    unsigned short* __restrict__ Wtg)
{
    const int b = blockIdx.x;
    const int t = threadIdx.x;
    if (b < CVT_BLOCKS) {
        const size_t base = ((size_t)b * 256 + t) * 8;
        const float4 v0 = *(const float4*)(x + base);
        const float4 v1 = *(const float4*)(x + base + 4);
        ushort4 o0, o1;
        o0.x = bf16_bits(v0.x); o0.y = bf16_bits(v0.y);
        o0.z = bf16_bits(v0.z); o0.w = bf16_bits(v0.w);
        o1.x = bf16_bits(v1.x); o1.y = bf16_bits(v1.y);
        o1.z = bf16_bits(v1.z); o1.w = bf16_bits(v1.w);
        *(ushort4*)(xb + base) = o0;
        *(ushort4*)(xb + base + 4) = o1;
        return;
    }
    if (b < CVT_BLOCKS + HIST_BLOCKS) {
        const int e = (b - CVT_BLOCKS) * 256 + t;
        rank[e] = atomicAdd(&counts[ei[N_EDGES + e]], 1);
        return;
    }
    // prep: Wtg[32h+o][k] = W[h][k][o]
    #pragma unroll
    for (int i = 0; i < 64; ++i) {
        const int idx = t + i * 256;           // 16384 f32
        const int h = idx >> 12;
        const int k = (idx >> 5) & 127;
        const int o = idx & 31;
        Wtg[(size_t)(h * 32 + o) * WPITCH + k] = bf16_bits(W[idx]);
    }
}

// K2: MFMA projection + fused attn dots.
// Block = 64 nodes x 128 cols, K=128. Wave w = m-tile w; 8 col-tiles.
__global__ __launch_bounds__(256, 2) void k_proj(
    const unsigned short* __restrict__ xb, const unsigned short* __restrict__ Wtg,
    const float* __restrict__ a_src, const float* __restrict__ a_dst,
    unsigned short* __restrict__ h_u16, float* __restrict__ attn_s4,
    float* __restrict__ attn_d4)
{
    __shared__ unsigned short xls[64 * WPITCH];    // 17408 B
    __shared__ unsigned short wls[128 * WPITCH];   // 34816 B
    const int t = threadIdx.x;
    const int base = blockIdx.x * 64;

    {   // stage Wt (flat copy, already padded): 2176 uint4
        const uint4* src = (const uint4*)Wtg;
        uint4* dst = (uint4*)wls;
        for (int i = t; i < 2176; i += 256) dst[i] = src[i];
    }
    {   // stage x tile: 64 rows x 16 uint4, dest pitch 17
        uint4* dst = (uint4*)xls;
        #pragma unroll
        for (int i = 0; i < 4; ++i) {
            const int idx = t + i * 256;           // 0..1023
            const int row = idx >> 4;
            const int c = idx & 15;
            const int node = base + row;
            uint4 v = make_uint4(0u, 0u, 0u, 0u);
            if (node < N_NODES)
                v = ((const uint4*)xb)[(size_t)node * 16 + c];
            dst[row * 17 + c] = v;
        }
    }
    __syncthreads();

    const int w = t >> 6;                          // m-tile 0..3
    const int lane = t & 63;
    const int lr = lane & 15;                      // A-row / B-col
    const int lq = lane >> 4;                      // k-quadrant

    const unsigned short* ap = &xls[(w * 16 + lr) * WPITCH + lq * 8];
    const unsigned short* bp = &wls[lr * WPITCH + lq * 8];

    f32x4 acc[8];
    #pragma unroll
    for (int ct = 0; ct < 8; ++ct) acc[ct] = (f32x4){0.f, 0.f, 0.f, 0.f};

    #pragma unroll
    for (int ks = 0; ks < 4; ++ks) {
        const bf16x8 a = *(const bf16x8*)(ap + ks * 32);
        #pragma unroll
        for (int ct = 0; ct < 8; ++ct) {
            const bf16x8 bv = *(const bf16x8*)(bp + ct * 16 * WPITCH + ks * 32);
            acc[ct] = __builtin_amdgcn_mfma_f32_16x16x32_bf16(a, bv, acc[ct], 0, 0, 0);
        }
    }

    // h store: node = base + 16w + lq*4 + r, col = ct*16 + lr
    const int nodeq = base + w * 16 + lq * 4;
    #pragma unroll
    for (int r = 0; r < 4; ++r) {
        const int node = nodeq + r;
        if (node >= N_NODES) continue;
        unsigned short* hrow = h_u16 + (size_t)node * 128 + lr;
        #pragma unroll
        for (int ct = 0; ct < 8; ++ct)
            hrow[ct * 16] = bf16_bits(acc[ct][r]);
    }

    // fused attn dots: per (head,r) reduce 2-col partials over 16 lr-lanes
    float asv[8], adv[8];
    #pragma unroll
    for (int h = 0; h < 4; ++h) {
        asv[2 * h]     = a_src[32 * h + lr];
        asv[2 * h + 1] = a_src[32 * h + 16 + lr];
        adv[2 * h]     = a_dst[32 * h + lr];
        adv[2 * h + 1] = a_dst[32 * h + 16 + lr];
    }
    #pragma unroll
    for (int h = 0; h < 4; ++h) {
        #pragma unroll
        for (int r = 0; r < 4; ++r) {
            float ps = acc[2 * h][r] * asv[2 * h] + acc[2 * h + 1][r] * asv[2 * h + 1];
            float pd = acc[2 * h][r] * adv[2 * h] + acc[2 * h + 1][r] * adv[2 * h + 1];
            #pragma unroll
            for (int m = 8; m >= 1; m >>= 1) {
                ps += __shfl_xor(ps, m);
                pd += __shfl_xor(pd, m);
            }
            const int node = nodeq + r;
            if (lr == 0 && node < N_NODES) {
                attn_s4[node * HEADS + h] = ps;
                attn_d4[node * HEADS + h] = pd;
            }
        }
    }
}

// K3a/b/c: scan of counts -> offsets
__global__ __launch_bounds__(256) void k_scan_part(
    const int* __restrict__ counts, int* __restrict__ bsum)
{
    const int i = blockIdx.x * 256 + threadIdx.x;
    int v = (i < N_NODES) ? counts[i] : 0;
    #pragma unroll
    for (int s = 32; s >= 1; s >>= 1) v += __shfl_xor(v, s);
    __shared__ int w[4];
    if ((threadIdx.x & 63) == 0) w[threadIdx.x >> 6] = v;
    __syncthreads();
    if (threadIdx.x == 0) bsum[blockIdx.x] = (w[0] + w[1]) + (w[2] + w[3]);
}
__global__ __launch_bounds__(256) void k_scan_base(
    const int* __restrict__ bsum, int* __restrict__ bbase)
{
    __shared__ int arr[256];
    const int t = threadIdx.x;
    arr[t] = (t < SCAN_B) ? bsum[t] : 0;
    __syncthreads();
    for (int d = 1; d < 256; d <<= 1) {
        const int v = (t >= d) ? arr[t - d] : 0;
        __syncthreads();
        arr[t] += v;
        __syncthreads();
    }
    bbase[t] = (t == 0) ? 0 : arr[t - 1];
}
__global__ __launch_bounds__(256) void k_scan_apply(
    const int* __restrict__ counts, const int* __restrict__ bbase,
    int* __restrict__ offsets)
{
    __shared__ int arr[256];
    const int t = threadIdx.x;
    const int i = blockIdx.x * 256 + t;
    const int c = (i < N_NODES) ? counts[i] : 0;
    arr[t] = c;
    __syncthreads();
    for (int d = 1; d < 256; d <<= 1) {
        const int v = (t >= d) ? arr[t - d] : 0;
        __syncthreads();
        arr[t] += v;
        __syncthreads();
    }
    const int incl = arr[t];
    const int base = bbase[blockIdx.x];
    if (i < N_NODES) offsets[i] = base + incl - c;
    if (i == N_NODES - 1) offsets[N_NODES] = base + incl;
}

// K4: atomic-free reorder, 4 B/edge: rec = (src16 << 16) | fp16(weight)
__global__ __launch_bounds__(256) void k_reorder(
    const int* __restrict__ ei, const float* __restrict__ ew,
    const int* __restrict__ rank, const int* __restrict__ offsets,
    unsigned* __restrict__ rec)
{
    const int e = blockIdx.x * 256 + threadIdx.x;   // grid covers E exactly
    const int src = ei[e];
    const int dst = ei[N_EDGES + e];
    const float w = ew[e];
    const int pos = offsets[dst] + rank[e];
    rec[pos] = ((unsigned)src << 16) | (unsigned)f16_bits(w);
}

// K5: per-dst gather-aggregate with on-the-fly logit+exp.
// Wave per dst; thread owns 2 adjacent cols (u32 = 2 bf16). Every lane
// holds the full denominator -> no cross-lane reduction.
__global__ __launch_bounds__(256) void k_aggregate(
    const unsigned* __restrict__ rec, const int* __restrict__ offsets,
    const float* __restrict__ attn_s4, const float* __restrict__ attn_d4,
    const unsigned* __restrict__ h32, float* __restrict__ out)
{
    const int l = threadIdx.x & 63;
    const int head = l >> 4;
    const int wid = blockIdx.x * 4 + (threadIdx.x >> 6);
    const unsigned* hp = h32 + l;

    for (int dst = wid; dst < N_NODES; dst += AGG_WAVES) {
        const int beg = offsets[dst];
        const int end = offsets[dst + 1];
        const float ad = attn_d4[dst * HEADS + head];
        float den = 0.f;
        float a0 = 0.f, a1 = 0.f, a2 = 0.f, a3 = 0.f;
        float b0 = 0.f, b1 = 0.f, b2 = 0.f, b3 = 0.f;
        int e = beg;
        for (; e + 4 <= end; e += 4) {
            const unsigned u0 = rec[e + 0], u1 = rec[e + 1];
            const unsigned u2 = rec[e + 2], u3 = rec[e + 3];
            const int s0 = u0 >> 16, s1 = u1 >> 16;
            const int s2 = u2 >> 16, s3 = u3 >> 16;
            float l0 = attn_s4[s0 * HEADS + head] + ad;
            float l1 = attn_s4[s1 * HEADS + head] + ad;
            float l2 = attn_s4[s2 * HEADS + head] + ad;
            float l3 = attn_s4[s3 * HEADS + head] + ad;
            l0 = ((l0 >= 0.f) ? l0 : NEG_SLOPE * l0) * f16u(u0 & 0xffffu);
            l1 = ((l1 >= 0.f) ? l1 : NEG_SLOPE * l1) * f16u(u1 & 0xffffu);
            l2 = ((l2 >= 0.f) ? l2 : NEG_SLOPE * l2) * f16u(u2 & 0xffffu);
            l3 = ((l3 >= 0.f) ? l3 : NEG_SLOPE * l3) * f16u(u3 & 0xffffu);
            const float p0 = __expf(l0), p1 = __expf(l1);
            const float p2 = __expf(l2), p3 = __expf(l3);
            const unsigned h0 = hp[(size_t)s0 * 64];
            const unsigned h1 = hp[(size_t)s1 * 64];
            const unsigned h2 = hp[(size_t)s2 * 64];
            const unsigned h3 = hp[(size_t)s3 * 64];
            a0 = fmaf(p0, __uint_as_float(h0 << 16), a0);
            b0 = fmaf(p0, __uint_as_float(h0 & 0xffff0000u), b0);
            a1 = fmaf(p1, __uint_as_float(h1 << 16), a1);
            b1 = fmaf(p1, __uint_as_float(h1 & 0xffff0000u), b1);
            a2 = fmaf(p2, __uint_as_float(h2 << 16), a2);
            b2 = fmaf(p2, __uint_as_float(h2 & 0xffff0000u), b2);
            a3 = fmaf(p3, __uint_as_float(h3 << 16), a3);
            b3 = fmaf(p3, __uint_as_float(h3 & 0xffff0000u), b3);
            den += (p0 + p1) + (p2 + p3);
        }
        for (; e < end; ++e) {
            const unsigned u = rec[e];
            const int s = u >> 16;
            float lv = attn_s4[s * HEADS + head] + ad;
            lv = ((lv >= 0.f) ? lv : NEG_SLOPE * lv) * f16u(u & 0xffffu);
            const float p = __expf(lv);
            const unsigned h = hp[(size_t)s * 64];
            a0 = fmaf(p, __uint_as_float(h << 16), a0);
            b0 = fmaf(p, __uint_as_float(h & 0xffff0000u), b0);
            den += p;
        }
        const float inv = 1.f / (den + 1e-10f);
        float2 o;
        o.x = ((a0 + a1) + (a2 + a3)) * inv;
        o.y = ((b0 + b1) + (b2 + b3)) * inv;
        ((float2*)out)[(size_t)dst * 64 + l] = o;
    }
}

extern "C" void kernel_launch(void* const* d_in, const int* in_sizes, int n_in,
                              void* d_out, int out_size, void* d_ws, size_t ws_size,
                              hipStream_t stream) {
    const float* x   = (const float*)d_in[0];
    const int*   ei  = (const int*)d_in[1];
    const float* ew  = (const float*)d_in[2];
    const float* W   = (const float*)d_in[3];
    const float* a_s = (const float*)d_in[4];
    const float* a_d = (const float*)d_in[5];
    float* out = (float*)d_out;

    unsigned* h32        = (unsigned*)d_ws;                          // 12.8 MB
    float*    attn_s4    = (float*)(h32 + (size_t)N_NODES * 64);     // 800 KB
    float*    attn_d4    = attn_s4 + (size_t)N_NODES * HEADS;        // 800 KB
    unsigned* rec        = (unsigned*)(attn_d4 + (size_t)N_NODES * HEADS); // 6.4 MB
    unsigned short* xb   = (unsigned short*)(rec + N_EDGES);         // 12.8 MB
    unsigned short* Wtg  = xb + (size_t)N_NODES * 128;               // 34.8 KB
    int*      rank       = (int*)(Wtg + 128 * WPITCH);               // 6.4 MB
    int*      counts     = rank + N_EDGES;                           // 200 KB
    int*      offsets    = counts + N_NODES;                         // 200 KB
    int*      bsum       = offsets + N_NODES + 1;
    int*      bbase      = bsum + 256;

    hipMemsetAsync(counts, 0, N_NODES * sizeof(int), stream);

    k_front<<<CVT_BLOCKS + HIST_BLOCKS + 1, 256, 0, stream>>>(
        x, xb, ei, counts, rank, W, Wtg);
    k_proj<<<PROJ_BLOCKS, 256, 0, stream>>>(xb, Wtg, a_s, a_d,
                                            (unsigned short*)h32,
                                            attn_s4, attn_d4);
    k_scan_part <<<SCAN_B, 256, 0, stream>>>(counts, bsum);
    k_scan_base <<<1, 256, 0, stream>>>(bsum, bbase);
    k_scan_apply<<<SCAN_B, 256, 0, stream>>>(counts, bbase, offsets);
    k_reorder<<<N_EDGES / 256, 256, 0, stream>>>(ei, ew, rank, offsets, rec);
    k_aggregate<<<AGG_BLOCKS, 256, 0, stream>>>(rec, offsets, attn_s4,
                                                attn_d4, h32, out);
}

// Round 15
// 171.923 us; speedup vs baseline: 2.1335x; 1.2550x over previous
//
#include <hip/hip_runtime.h>
#include <hip/hip_bf16.h>
#include <hip/hip_fp16.h>

#define N_NODES 50000
#define N_EDGES 1600000
#define IN_F 128
#define OUT_F 32
#define HEADS 4
#define NEG_SLOPE 0.2f
#define HO (HEADS * OUT_F)

#define NBUCKET 1563                           // ceil(N_NODES / 32)
#define BBLK 256                               // histogram/scatter blocks
#define EPB (N_EDGES / BBLK)                   // 6250 edges per block
#define PROJ_BLOCKS ((N_NODES + 63) / 64)      // 782
#define AGG_BLOCKS 3125
#define AGG_WAVES (AGG_BLOCKS * 4)
#define WPITCH 136                             // bf16 pitch (17 x b128)

typedef __attribute__((ext_vector_type(8))) short bf16x8;
typedef __attribute__((ext_vector_type(4))) float f32x4;

__device__ __forceinline__ unsigned short bf16_bits(float f) {
    union { __hip_bfloat16 b; unsigned short u; } cv;
    cv.b = __float2bfloat16(f);
    return cv.u;
}
__device__ __forceinline__ unsigned short f16_bits(float f) {
    union { __half h; unsigned short u; } cv;
    cv.h = __float2half(f);
    return cv.u;
}
__device__ __forceinline__ float f16u(unsigned short u) {
    union { unsigned short x; __half h; } cv;
    cv.x = u;
    return __half2float(cv.h);
}

// K1: blocks [0,256): per-block LDS histogram over 1563 coarse buckets
//     (dst>>5), coalesced dump to bhist[blk][bucket]. NO device atomics.
//     blocks [256,264): transpose W -> Wtg[32h+o][k] bf16 (pitch 136).
__global__ __launch_bounds__(256) void k_bhist(
    const int* __restrict__ ei, int* __restrict__ bhist,
    const float* __restrict__ W, unsigned short* __restrict__ Wtg)
{
    const int blk = blockIdx.x;
    const int t = threadIdx.x;
    if (blk >= BBLK) {                          // W prep
        const int bp = blk - BBLK;
        #pragma unroll
        for (int i = 0; i < 8; ++i) {
            const int idx = bp * 2048 + t + i * 256;   // 16384 f32 total
            const int h = idx >> 12;
            const int k = (idx >> 5) & 127;
            const int o = idx & 31;
            Wtg[(size_t)(h * 32 + o) * WPITCH + k] = bf16_bits(W[idx]);
        }
        return;
    }
    __shared__ int lhist[NBUCKET];
    for (int i = t; i < NBUCKET; i += 256) lhist[i] = 0;
    __syncthreads();
    const int* dstp = ei + N_EDGES + blk * EPB;
    for (int i = t; i < EPB; i += 256)
        atomicAdd(&lhist[dstp[i] >> 5], 1);
    __syncthreads();
    int* dump = bhist + (size_t)blk * NBUCKET;
    for (int i = t; i < NBUCKET; i += 256) dump[i] = lhist[i];
}

// K2: MFMA projection + fused attn dots; x converted f32->bf16 in staging.
__global__ __launch_bounds__(256, 2) void k_proj(
    const float* __restrict__ x, const unsigned short* __restrict__ Wtg,
    const float* __restrict__ a_src, const float* __restrict__ a_dst,
    unsigned short* __restrict__ h_u16, float* __restrict__ attn_s4,
    float* __restrict__ attn_d4)
{
    __shared__ unsigned short xls[64 * WPITCH];    // 17408 B
    __shared__ unsigned short wls[128 * WPITCH];   // 34816 B
    const int t = threadIdx.x;
    const int base = blockIdx.x * 64;

    {   // stage Wt (flat copy, already padded): 2176 uint4
        const uint4* src = (const uint4*)Wtg;
        uint4* dst = (uint4*)wls;
        for (int i = t; i < 2176; i += 256) dst[i] = src[i];
    }
    {   // stage x tile: 64 rows x 32 float4, convert to bf16
        const float4* xsrc = (const float4*)x + (size_t)base * 32;
        #pragma unroll
        for (int i = 0; i < 8; ++i) {
            const int idx = t + i * 256;           // 0..2047
            const int row = idx >> 5;
            const int c4 = idx & 31;
            float4 v = {0.f, 0.f, 0.f, 0.f};
            if (base + row < N_NODES) v = xsrc[row * 32 + c4];
            ushort4 o;
            o.x = bf16_bits(v.x); o.y = bf16_bits(v.y);
            o.z = bf16_bits(v.z); o.w = bf16_bits(v.w);
            *(ushort4*)&xls[row * WPITCH + c4 * 4] = o;
        }
    }
    __syncthreads();

    const int w = t >> 6;                          // m-tile 0..3
    const int lane = t & 63;
    const int lr = lane & 15;                      // A-row / B-col
    const int lq = lane >> 4;                      // k-quadrant

    const unsigned short* ap = &xls[(w * 16 + lr) * WPITCH + lq * 8];
    const unsigned short* bp = &wls[lr * WPITCH + lq * 8];

    f32x4 acc[8];
    #pragma unroll
    for (int ct = 0; ct < 8; ++ct) acc[ct] = (f32x4){0.f, 0.f, 0.f, 0.f};

    #pragma unroll
    for (int ks = 0; ks < 4; ++ks) {
        const bf16x8 a = *(const bf16x8*)(ap + ks * 32);
        #pragma unroll
        for (int ct = 0; ct < 8; ++ct) {
            const bf16x8 bv = *(const bf16x8*)(bp + ct * 16 * WPITCH + ks * 32);
            acc[ct] = __builtin_amdgcn_mfma_f32_16x16x32_bf16(a, bv, acc[ct], 0, 0, 0);
        }
    }

    // h store: node = base + 16w + lq*4 + r, col = ct*16 + lr
    const int nodeq = base + w * 16 + lq * 4;
    #pragma unroll
    for (int r = 0; r < 4; ++r) {
        const int node = nodeq + r;
        if (node >= N_NODES) continue;
        unsigned short* hrow = h_u16 + (size_t)node * 128 + lr;
        #pragma unroll
        for (int ct = 0; ct < 8; ++ct)
            hrow[ct * 16] = bf16_bits(acc[ct][r]);
    }

    // fused attn dots
    float asv[8], adv[8];
    #pragma unroll
    for (int h = 0; h < 4; ++h) {
        asv[2 * h]     = a_src[32 * h + lr];
        asv[2 * h + 1] = a_src[32 * h + 16 + lr];
        adv[2 * h]     = a_dst[32 * h + lr];
        adv[2 * h + 1] = a_dst[32 * h + 16 + lr];
    }
    #pragma unroll
    for (int h = 0; h < 4; ++h) {
        #pragma unroll
        for (int r = 0; r < 4; ++r) {
            float ps = acc[2 * h][r] * asv[2 * h] + acc[2 * h + 1][r] * asv[2 * h + 1];
            float pd = acc[2 * h][r] * adv[2 * h] + acc[2 * h + 1][r] * adv[2 * h + 1];
            #pragma unroll
            for (int m = 8; m >= 1; m >>= 1) {
                ps += __shfl_xor(ps, m);
                pd += __shfl_xor(pd, m);
            }
            const int node = nodeq + r;
            if (lr == 0 && node < N_NODES) {
                attn_s4[node * HEADS + h] = ps;
                attn_d4[node * HEADS + h] = pd;
            }
        }
    }
}

// K3: column exclusive scan of bhist over the 256 block rows.
// thread j walks its bucket column; loads batched 8-deep (coalesced rows).
__global__ __launch_bounds__(256) void k_colscan(
    int* __restrict__ bhist, int* __restrict__ btotal)
{
    const int j = blockIdx.x * 256 + threadIdx.x;
    if (j >= NBUCKET) return;
    int run = 0;
    for (int blk = 0; blk < BBLK; blk += 8) {
        int v[8];
        #pragma unroll
        for (int q = 0; q < 8; ++q)
            v[q] = bhist[(size_t)(blk + q) * NBUCKET + j];
        #pragma unroll
        for (int q = 0; q < 8; ++q) {
            const int nv = v[q];
            bhist[(size_t)(blk + q) * NBUCKET + j] = run;
            run += nv;
        }
    }
    btotal[j] = run;
}

// K4: exclusive scan of bucket totals -> bbase (single block)
__global__ __launch_bounds__(256) void k_bbase(
    const int* __restrict__ btotal, int* __restrict__ bbase,
    int* __restrict__ offsets)
{
    __shared__ int part[256];
    const int t = threadIdx.x;
    const int CH = 7;                              // 7*256 >= 1563
    const int lo = t * CH;
    const int hi = min(lo + CH, NBUCKET);
    int s = 0;
    for (int i = lo; i < hi; ++i) s += btotal[i];
    part[t] = s;
    __syncthreads();
    for (int d = 1; d < 256; d <<= 1) {
        const int v = (t >= d) ? part[t - d] : 0;
        __syncthreads();
        part[t] += v;
        __syncthreads();
    }
    int base = (t == 0) ? 0 : part[t - 1];
    for (int i = lo; i < hi; ++i) {
        bbase[i] = base;
        base += btotal[i];
    }
    if (t == 0) offsets[N_NODES] = N_EDGES;
}

// K5: scatter edges into bucket-sorted order via LDS cursors (atomic-free
// at device scope). brec = (src16<<16)|fp16(w); bldst = dst & 31.
__global__ __launch_bounds__(256) void k_bscatter(
    const int* __restrict__ ei, const float* __restrict__ ew,
    const int* __restrict__ bhist, const int* __restrict__ bbase,
    unsigned* __restrict__ brec, unsigned char* __restrict__ bldst)
{
    __shared__ int cur[NBUCKET];
    const int blk = blockIdx.x;
    const int t = threadIdx.x;
    const int* row = bhist + (size_t)blk * NBUCKET;
    for (int i = t; i < NBUCKET; i += 256) cur[i] = bbase[i] + row[i];
    __syncthreads();
    const int* srcp = ei + blk * EPB;
    const int* dstp = ei + N_EDGES + blk * EPB;
    const float* wp = ew + blk * EPB;
    for (int i = t; i < EPB; i += 256) {
        const int src = srcp[i];
        const int dst = dstp[i];
        const float w = wp[i];
        const int pos = atomicAdd(&cur[dst >> 5], 1);
        brec[pos] = ((unsigned)src << 16) | (unsigned)f16_bits(w);
        bldst[pos] = (unsigned char)(dst & 31);
    }
}

// K6: finish within each bucket (32 dsts): 32-bin LDS hist + scan ->
// final dst-sorted rec + per-dst offsets. Two-pass from global (L2-hot).
__global__ __launch_bounds__(256) void k_bfinish(
    const unsigned* __restrict__ brec, const unsigned char* __restrict__ bldst,
    const int* __restrict__ bbase, const int* __restrict__ btotal,
    unsigned* __restrict__ rec, int* __restrict__ offsets)
{
    __shared__ int bin[32], bcur[32];
    const int j = blockIdx.x;
    const int t = threadIdx.x;
    const int start = bbase[j];
    const int n = btotal[j];
    if (t < 32) bin[t] = 0;
    __syncthreads();
    for (int i = t; i < n; i += 256)
        atomicAdd(&bin[bldst[start + i]], 1);
    __syncthreads();
    if (t == 0) {
        int run = 0;
        #pragma unroll
        for (int b = 0; b < 32; ++b) { bcur[b] = run; run += bin[b]; }
    }
    __syncthreads();
    if (t < 32) {
        const int d = j * 32 + t;
        if (d < N_NODES) offsets[d] = start + bcur[t];
    }
    __syncthreads();
    for (int i = t; i < n; i += 256) {
        const unsigned u = brec[start + i];
        const int b = bldst[start + i];
        const int pos = start + atomicAdd(&bcur[b], 1);
        rec[pos] = u;
    }
}

// K7: per-dst gather-aggregate with on-the-fly logit+exp (round-14, good).
__global__ __launch_bounds__(256) void k_aggregate(
    const unsigned* __restrict__ rec, const int* __restrict__ offsets,
    const float* __restrict__ attn_s4, const float* __restrict__ attn_d4,
    const unsigned* __restrict__ h32, float* __restrict__ out)
{
    const int l = threadIdx.x & 63;
    const int head = l >> 4;
    const int wid = blockIdx.x * 4 + (threadIdx.x >> 6);
    const unsigned* hp = h32 + l;

    for (int dst = wid; dst < N_NODES; dst += AGG_WAVES) {
        const int beg = offsets[dst];
        const int end = offsets[dst + 1];
        const float ad = attn_d4[dst * HEADS + head];
        float den = 0.f;
        float a0 = 0.f, a1 = 0.f, a2 = 0.f, a3 = 0.f;
        float b0 = 0.f, b1 = 0.f, b2 = 0.f, b3 = 0.f;
        int e = beg;
        for (; e + 4 <= end; e += 4) {
            const unsigned u0 = rec[e + 0], u1 = rec[e + 1];
            const unsigned u2 = rec[e + 2], u3 = rec[e + 3];
            const int s0 = u0 >> 16, s1 = u1 >> 16;
            const int s2 = u2 >> 16, s3 = u3 >> 16;
            float l0 = attn_s4[s0 * HEADS + head] + ad;
            float l1 = attn_s4[s1 * HEADS + head] + ad;
            float l2 = attn_s4[s2 * HEADS + head] + ad;
            float l3 = attn_s4[s3 * HEADS + head] + ad;
            l0 = ((l0 >= 0.f) ? l0 : NEG_SLOPE * l0) * f16u(u0 & 0xffffu);
            l1 = ((l1 >= 0.f) ? l1 : NEG_SLOPE * l1) * f16u(u1 & 0xffffu);
            l2 = ((l2 >= 0.f) ? l2 : NEG_SLOPE * l2) * f16u(u2 & 0xffffu);
            l3 = ((l3 >= 0.f) ? l3 : NEG_SLOPE * l3) * f16u(u3 & 0xffffu);
            const float p0 = __expf(l0), p1 = __expf(l1);
            const float p2 = __expf(l2), p3 = __expf(l3);
            const unsigned h0 = hp[(size_t)s0 * 64];
            const unsigned h1 = hp[(size_t)s1 * 64];
            const unsigned h2 = hp[(size_t)s2 * 64];
            const unsigned h3 = hp[(size_t)s3 * 64];
            a0 = fmaf(p0, __uint_as_float(h0 << 16), a0);
            b0 = fmaf(p0, __uint_as_float(h0 & 0xffff0000u), b0);
            a1 = fmaf(p1, __uint_as_float(h1 << 16), a1);
            b1 = fmaf(p1, __uint_as_float(h1 & 0xffff0000u), b1);
            a2 = fmaf(p2, __uint_as_float(h2 << 16), a2);
            b2 = fmaf(p2, __uint_as_float(h2 & 0xffff0000u), b2);
            a3 = fmaf(p3, __uint_as_float(h3 << 16), a3);
            b3 = fmaf(p3, __uint_as_float(h3 & 0xffff0000u), b3);
            den += (p0 + p1) + (p2 + p3);
        }
        for (; e < end; ++e) {
            const unsigned u = rec[e];
            const int s = u >> 16;
            float lv = attn_s4[s * HEADS + head] + ad;
            lv = ((lv >= 0.f) ? lv : NEG_SLOPE * lv) * f16u(u & 0xffffu);
            const float p = __expf(lv);
            const unsigned h = hp[(size_t)s * 64];
            a0 = fmaf(p, __uint_as_float(h << 16), a0);
            b0 = fmaf(p, __uint_as_float(h & 0xffff0000u), b0);
            den += p;
        }
        const float inv = 1.f / (den + 1e-10f);
        float2 o;
        o.x = ((a0 + a1) + (a2 + a3)) * inv;
        o.y = ((b0 + b1) + (b2 + b3)) * inv;
        ((float2*)out)[(size_t)dst * 64 + l] = o;
    }
}

extern "C" void kernel_launch(void* const* d_in, const int* in_sizes, int n_in,
                              void* d_out, int out_size, void* d_ws, size_t ws_size,
                              hipStream_t stream) {
    const float* x   = (const float*)d_in[0];
    const int*   ei  = (const int*)d_in[1];
    const float* ew  = (const float*)d_in[2];
    const float* W   = (const float*)d_in[3];
    const float* a_s = (const float*)d_in[4];
    const float* a_d = (const float*)d_in[5];
    float* out = (float*)d_out;

    unsigned* h32     = (unsigned*)d_ws;                          // 12.8 MB
    float*    attn_s4 = (float*)(h32 + (size_t)N_NODES * 64);     // 800 KB
    float*    attn_d4 = attn_s4 + (size_t)N_NODES * HEADS;        // 800 KB
    unsigned* rec     = (unsigned*)(attn_d4 + (size_t)N_NODES * HEADS); // 6.4 MB
    unsigned* brec    = rec + N_EDGES;                            // 6.4 MB
    int*      bhist   = (int*)(brec + N_EDGES);                   // 1.6 MB
    int*      btotal  = bhist + BBLK * NBUCKET;                   // 6.3 KB
    int*      bbase   = btotal + NBUCKET;                         // 6.3 KB
    int*      offsets = bbase + NBUCKET;                          // 200 KB
    unsigned char* bldst = (unsigned char*)(offsets + N_NODES + 1); // 1.6 MB
    unsigned short* Wtg  = (unsigned short*)(bldst + N_EDGES);    // 35 KB

    k_bhist<<<BBLK + 8, 256, 0, stream>>>(ei, bhist, W, Wtg);
    k_proj<<<PROJ_BLOCKS, 256, 0, stream>>>(x, Wtg, a_s, a_d,
                                            (unsigned short*)h32,
                                            attn_s4, attn_d4);
    k_colscan<<<(NBUCKET + 255) / 256, 256, 0, stream>>>(bhist, btotal);
    k_bbase<<<1, 256, 0, stream>>>(btotal, bbase, offsets);
    k_bscatter<<<BBLK, 256, 0, stream>>>(ei, ew, bhist, bbase, brec, bldst);
    k_bfinish<<<NBUCKET, 256, 0, stream>>>(brec, bldst, bbase, btotal,
                                           rec, offsets);
    k_aggregate<<<AGG_BLOCKS, 256, 0, stream>>>(rec, offsets, attn_s4,
                                                attn_d4, h32, out);
}

// Round 16
// 164.227 us; speedup vs baseline: 2.2335x; 1.0469x over previous
//
#include <hip/hip_runtime.h>
#include <hip/hip_bf16.h>
#include <hip/hip_fp16.h>

#define N_NODES 50000
#define N_EDGES 1600000
#define IN_F 128
#define OUT_F 32
#define HEADS 4
#define NEG_SLOPE 0.2f
#define HO (HEADS * OUT_F)

#define NBUCKET 1563                           // ceil(N_NODES / 32)
#define BBLK 256                               // histogram/scatter blocks
#define EPB (N_EDGES / BBLK)                   // 6250 edges per block
#define PROJ_BLOCKS ((N_NODES + 63) / 64)      // 782
#define AGG_BLOCKS 3125
#define AGG_WAVES (AGG_BLOCKS * 4)
#define WPITCH 136                             // bf16 pitch (17 x b128)

typedef __attribute__((ext_vector_type(8))) short bf16x8;
typedef __attribute__((ext_vector_type(4))) float f32x4;

__device__ __forceinline__ unsigned short bf16_bits(float f) {
    union { __hip_bfloat16 b; unsigned short u; } cv;
    cv.b = __float2bfloat16(f);
    return cv.u;
}
__device__ __forceinline__ unsigned short f16_bits(float f) {
    union { __half h; unsigned short u; } cv;
    cv.h = __float2half(f);
    return cv.u;
}
__device__ __forceinline__ float f16u(unsigned short u) {
    union { unsigned short x; __half h; } cv;
    cv.x = u;
    return __half2float(cv.h);
}

// K1: blocks [0,256): per-block LDS histogram over 1563 coarse buckets
//     (dst>>5), coalesced dump to bhist[blk][bucket]. NO device atomics.
//     blocks [256,264): transpose W -> Wtg[32h+o][k] bf16 (pitch 136).
__global__ __launch_bounds__(256) void k_bhist(
    const int* __restrict__ ei, int* __restrict__ bhist,
    const float* __restrict__ W, unsigned short* __restrict__ Wtg)
{
    const int blk = blockIdx.x;
    const int t = threadIdx.x;
    if (blk >= BBLK) {                          // W prep
        const int bp = blk - BBLK;
        #pragma unroll
        for (int i = 0; i < 8; ++i) {
            const int idx = bp * 2048 + t + i * 256;   // 16384 f32 total
            const int h = idx >> 12;
            const int k = (idx >> 5) & 127;
            const int o = idx & 31;
            Wtg[(size_t)(h * 32 + o) * WPITCH + k] = bf16_bits(W[idx]);
        }
        return;
    }
    __shared__ int lhist[NBUCKET];
    for (int i = t; i < NBUCKET; i += 256) lhist[i] = 0;
    __syncthreads();
    const int* dstp = ei + N_EDGES + blk * EPB;
    for (int i = t; i < EPB; i += 256)
        atomicAdd(&lhist[dstp[i] >> 5], 1);
    __syncthreads();
    int* dump = bhist + (size_t)blk * NBUCKET;
    for (int i = t; i < NBUCKET; i += 256) dump[i] = lhist[i];
}

// K2: MFMA projection + fused attn dots; x converted f32->bf16 in staging.
__global__ __launch_bounds__(256, 2) void k_proj(
    const float* __restrict__ x, const unsigned short* __restrict__ Wtg,
    const float* __restrict__ a_src, const float* __restrict__ a_dst,
    unsigned short* __restrict__ h_u16, float* __restrict__ attn_s4,
    float* __restrict__ attn_d4)
{
    __shared__ unsigned short xls[64 * WPITCH];    // 17408 B
    __shared__ unsigned short wls[128 * WPITCH];   // 34816 B
    const int t = threadIdx.x;
    const int base = blockIdx.x * 64;

    {   // stage Wt (flat copy, already padded): 2176 uint4
        const uint4* src = (const uint4*)Wtg;
        uint4* dst = (uint4*)wls;
        for (int i = t; i < 2176; i += 256) dst[i] = src[i];
    }
    {   // stage x tile: 64 rows x 32 float4, convert to bf16
        const float4* xsrc = (const float4*)x + (size_t)base * 32;
        #pragma unroll
        for (int i = 0; i < 8; ++i) {
            const int idx = t + i * 256;           // 0..2047
            const int row = idx >> 5;
            const int c4 = idx & 31;
            float4 v = {0.f, 0.f, 0.f, 0.f};
            if (base + row < N_NODES) v = xsrc[row * 32 + c4];
            ushort4 o;
            o.x = bf16_bits(v.x); o.y = bf16_bits(v.y);
            o.z = bf16_bits(v.z); o.w = bf16_bits(v.w);
            *(ushort4*)&xls[row * WPITCH + c4 * 4] = o;
        }
    }
    __syncthreads();

    const int w = t >> 6;                          // m-tile 0..3
    const int lane = t & 63;
    const int lr = lane & 15;                      // A-row / B-col
    const int lq = lane >> 4;                      // k-quadrant

    const unsigned short* ap = &xls[(w * 16 + lr) * WPITCH + lq * 8];
    const unsigned short* bp = &wls[lr * WPITCH + lq * 8];

    f32x4 acc[8];
    #pragma unroll
    for (int ct = 0; ct < 8; ++ct) acc[ct] = (f32x4){0.f, 0.f, 0.f, 0.f};

    #pragma unroll
    for (int ks = 0; ks < 4; ++ks) {
        const bf16x8 a = *(const bf16x8*)(ap + ks * 32);
        #pragma unroll
        for (int ct = 0; ct < 8; ++ct) {
            const bf16x8 bv = *(const bf16x8*)(bp + ct * 16 * WPITCH + ks * 32);
            acc[ct] = __builtin_amdgcn_mfma_f32_16x16x32_bf16(a, bv, acc[ct], 0, 0, 0);
        }
    }

    // h store: node = base + 16w + lq*4 + r, col = ct*16 + lr
    const int nodeq = base + w * 16 + lq * 4;
    #pragma unroll
    for (int r = 0; r < 4; ++r) {
        const int node = nodeq + r;
        if (node >= N_NODES) continue;
        unsigned short* hrow = h_u16 + (size_t)node * 128 + lr;
        #pragma unroll
        for (int ct = 0; ct < 8; ++ct)
            hrow[ct * 16] = bf16_bits(acc[ct][r]);
    }

    // fused attn dots
    float asv[8], adv[8];
    #pragma unroll
    for (int h = 0; h < 4; ++h) {
        asv[2 * h]     = a_src[32 * h + lr];
        asv[2 * h + 1] = a_src[32 * h + 16 + lr];
        adv[2 * h]     = a_dst[32 * h + lr];
        adv[2 * h + 1] = a_dst[32 * h + 16 + lr];
    }
    #pragma unroll
    for (int h = 0; h < 4; ++h) {
        #pragma unroll
        for (int r = 0; r < 4; ++r) {
            float ps = acc[2 * h][r] * asv[2 * h] + acc[2 * h + 1][r] * asv[2 * h + 1];
            float pd = acc[2 * h][r] * adv[2 * h] + acc[2 * h + 1][r] * adv[2 * h + 1];
            #pragma unroll
            for (int m = 8; m >= 1; m >>= 1) {
                ps += __shfl_xor(ps, m);
                pd += __shfl_xor(pd, m);
            }
            const int node = nodeq + r;
            if (lr == 0 && node < N_NODES) {
                attn_s4[node * HEADS + h] = ps;
                attn_d4[node * HEADS + h] = pd;
            }
        }
    }
}

// K3: column exclusive scan of bhist over the 256 block rows.
__global__ __launch_bounds__(256) void k_colscan(
    int* __restrict__ bhist, int* __restrict__ btotal)
{
    const int j = blockIdx.x * 256 + threadIdx.x;
    if (j >= NBUCKET) return;
    int run = 0;
    for (int blk = 0; blk < BBLK; blk += 8) {
        int v[8];
        #pragma unroll
        for (int q = 0; q < 8; ++q)
            v[q] = bhist[(size_t)(blk + q) * NBUCKET + j];
        #pragma unroll
        for (int q = 0; q < 8; ++q) {
            const int nv = v[q];
            bhist[(size_t)(blk + q) * NBUCKET + j] = run;
            run += nv;
        }
    }
    btotal[j] = run;
}

// K4: exclusive scan of bucket totals -> bbase (single block)
__global__ __launch_bounds__(256) void k_bbase(
    const int* __restrict__ btotal, int* __restrict__ bbase,
    int* __restrict__ offsets)
{
    __shared__ int part[256];
    const int t = threadIdx.x;
    const int CH = 7;                              // 7*256 >= 1563
    const int lo = t * CH;
    const int hi = min(lo + CH, NBUCKET);
    int s = 0;
    for (int i = lo; i < hi; ++i) s += btotal[i];
    part[t] = s;
    __syncthreads();
    for (int d = 1; d < 256; d <<= 1) {
        const int v = (t >= d) ? part[t - d] : 0;
        __syncthreads();
        part[t] += v;
        __syncthreads();
    }
    int base = (t == 0) ? 0 : part[t - 1];
    for (int i = lo; i < hi; ++i) {
        bbase[i] = base;
        base += btotal[i];
    }
    if (t == 0) offsets[N_NODES] = N_EDGES;
}

// K5: scatter edges into bucket-sorted order via LDS cursors.
__global__ __launch_bounds__(256) void k_bscatter(
    const int* __restrict__ ei, const float* __restrict__ ew,
    const int* __restrict__ bhist, const int* __restrict__ bbase,
    unsigned* __restrict__ brec, unsigned char* __restrict__ bldst)
{
    __shared__ int cur[NBUCKET];
    const int blk = blockIdx.x;
    const int t = threadIdx.x;
    const int* row = bhist + (size_t)blk * NBUCKET;
    for (int i = t; i < NBUCKET; i += 256) cur[i] = bbase[i] + row[i];
    __syncthreads();
    const int* srcp = ei + blk * EPB;
    const int* dstp = ei + N_EDGES + blk * EPB;
    const float* wp = ew + blk * EPB;
    for (int i = t; i < EPB; i += 256) {
        const int src = srcp[i];
        const int dst = dstp[i];
        const float w = wp[i];
        const int pos = atomicAdd(&cur[dst >> 5], 1);
        brec[pos] = ((unsigned)src << 16) | (unsigned)f16_bits(w);
        bldst[pos] = (unsigned char)(dst & 31);
    }
}

// K6: finish within each bucket (32 dsts): 32-bin LDS hist + scan ->
// final dst-sorted rec + per-dst offsets.
__global__ __launch_bounds__(256) void k_bfinish(
    const unsigned* __restrict__ brec, const unsigned char* __restrict__ bldst,
    const int* __restrict__ bbase, const int* __restrict__ btotal,
    unsigned* __restrict__ rec, int* __restrict__ offsets)
{
    __shared__ int bin[32], bcur[32];
    const int j = blockIdx.x;
    const int t = threadIdx.x;
    const int start = bbase[j];
    const int n = btotal[j];
    if (t < 32) bin[t] = 0;
    __syncthreads();
    for (int i = t; i < n; i += 256)
        atomicAdd(&bin[bldst[start + i]], 1);
    __syncthreads();
    if (t == 0) {
        int run = 0;
        #pragma unroll
        for (int b = 0; b < 32; ++b) { bcur[b] = run; run += bin[b]; }
    }
    __syncthreads();
    if (t < 32) {
        const int d = j * 32 + t;
        if (d < N_NODES) offsets[d] = start + bcur[t];
    }
    __syncthreads();
    for (int i = t; i < n; i += 256) {
        const unsigned u = brec[start + i];
        const int b = bldst[start + i];
        const int pos = start + atomicAdd(&bcur[b], 1);
        rec[pos] = u;
    }
}

// K7: per-dst gather-aggregate, LANE-PARALLEL p-phase.
// Per 16-edge chunk: lane l = (edge slot l&15, head l>>4) computes ONE
// distinct logit+exp (no 16x redundancy); p repacked as (src16|fp16 p);
// FMA phase: one __shfl(.,q,16) per edge, coalesced 256 B h-row gather.
// Every lane holds the full denominator -> no cross-lane reduction.
__global__ __launch_bounds__(256) void k_aggregate(
    const unsigned* __restrict__ rec, const int* __restrict__ offsets,
    const float* __restrict__ attn_s4, const float* __restrict__ attn_d4,
    const unsigned* __restrict__ h32, float* __restrict__ out)
{
    const int l = threadIdx.x & 63;
    const int le = l & 15;                         // edge slot
    const int lh = l >> 4;                         // head
    const int wid = blockIdx.x * 4 + (threadIdx.x >> 6);
    const unsigned* hp = h32 + l;

    for (int dst = wid; dst < N_NODES; dst += AGG_WAVES) {
        const int beg = offsets[dst];
        const int end = offsets[dst + 1];
        const float ad = attn_d4[dst * HEADS + lh];
        float den0 = 0.f, den1 = 0.f;
        float a0 = 0.f, a1 = 0.f, b0 = 0.f, b1 = 0.f;
        for (int c = beg; c < end; c += 16) {
            const int cnt = min(16, end - c);
            // ---- p-phase: each lane computes one (edge, head) exp ----
            unsigned pk = 0;
            if (le < cnt) {
                const unsigned u = rec[c + le];
                const int s = u >> 16;
                float lo = attn_s4[s * HEADS + lh] + ad;
                lo = ((lo >= 0.f) ? lo : NEG_SLOPE * lo) * f16u(u & 0xffffu);
                pk = (u & 0xffff0000u) | (unsigned)f16_bits(__expf(lo));
            }
            // ---- FMA phase: broadcast within own 16-lane (head) group ----
            if (cnt == 16) {
                #pragma unroll
                for (int q = 0; q < 16; q += 2) {
                    const unsigned k0 = (unsigned)__shfl((int)pk, q, 16);
                    const unsigned k1 = (unsigned)__shfl((int)pk, q + 1, 16);
                    const float p0 = f16u(k0 & 0xffffu);
                    const float p1 = f16u(k1 & 0xffffu);
                    const unsigned h0 = hp[(size_t)(k0 >> 16) * 64];
                    const unsigned h1 = hp[(size_t)(k1 >> 16) * 64];
                    a0 = fmaf(p0, __uint_as_float(h0 << 16), a0);
                    b0 = fmaf(p0, __uint_as_float(h0 & 0xffff0000u), b0);
                    a1 = fmaf(p1, __uint_as_float(h1 << 16), a1);
                    b1 = fmaf(p1, __uint_as_float(h1 & 0xffff0000u), b1);
                    den0 += p0;
                    den1 += p1;
                }
            } else {
                for (int q = 0; q < cnt; ++q) {
                    const unsigned k0 = (unsigned)__shfl((int)pk, q, 16);
                    const float p0 = f16u(k0 & 0xffffu);
                    const unsigned h0 = hp[(size_t)(k0 >> 16) * 64];
                    a0 = fmaf(p0, __uint_as_float(h0 << 16), a0);
                    b0 = fmaf(p0, __uint_as_float(h0 & 0xffff0000u), b0);
                    den0 += p0;
                }
            }
        }
        const float inv = 1.f / ((den0 + den1) + 1e-10f);
        float2 o;
        o.x = (a0 + a1) * inv;
        o.y = (b0 + b1) * inv;
        ((float2*)out)[(size_t)dst * 64 + l] = o;
    }
}

extern "C" void kernel_launch(void* const* d_in, const int* in_sizes, int n_in,
                              void* d_out, int out_size, void* d_ws, size_t ws_size,
                              hipStream_t stream) {
    const float* x   = (const float*)d_in[0];
    const int*   ei  = (const int*)d_in[1];
    const float* ew  = (const float*)d_in[2];
    const float* W   = (const float*)d_in[3];
    const float* a_s = (const float*)d_in[4];
    const float* a_d = (const float*)d_in[5];
    float* out = (float*)d_out;

    unsigned* h32     = (unsigned*)d_ws;                          // 12.8 MB
    float*    attn_s4 = (float*)(h32 + (size_t)N_NODES * 64);     // 800 KB
    float*    attn_d4 = attn_s4 + (size_t)N_NODES * HEADS;        // 800 KB
    unsigned* rec     = (unsigned*)(attn_d4 + (size_t)N_NODES * HEADS); // 6.4 MB
    unsigned* brec    = rec + N_EDGES;                            // 6.4 MB
    int*      bhist   = (int*)(brec + N_EDGES);                   // 1.6 MB
    int*      btotal  = bhist + BBLK * NBUCKET;                   // 6.3 KB
    int*      bbase   = btotal + NBUCKET;                         // 6.3 KB
    int*      offsets = bbase + NBUCKET;                          // 200 KB
    unsigned char* bldst = (unsigned char*)(offsets + N_NODES + 1); // 1.6 MB
    unsigned short* Wtg  = (unsigned short*)(bldst + N_EDGES);    // 35 KB

    k_bhist<<<BBLK + 8, 256, 0, stream>>>(ei, bhist, W, Wtg);
    k_proj<<<PROJ_BLOCKS, 256, 0, stream>>>(x, Wtg, a_s, a_d,
                                            (unsigned short*)h32,
                                            attn_s4, attn_d4);
    k_colscan<<<(NBUCKET + 255) / 256, 256, 0, stream>>>(bhist, btotal);
    k_bbase<<<1, 256, 0, stream>>>(btotal, bbase, offsets);
    k_bscatter<<<BBLK, 256, 0, stream>>>(ei, ew, bhist, bbase, brec, bldst);
    k_bfinish<<<NBUCKET, 256, 0, stream>>>(brec, bldst, bbase, btotal,
                                           rec, offsets);
    k_aggregate<<<AGG_BLOCKS, 256, 0, stream>>>(rec, offsets, attn_s4,
                                                attn_d4, h32, out);
}

// Round 17
// 152.089 us; speedup vs baseline: 2.4117x; 1.0798x over previous
//
#include <hip/hip_runtime.h>
#include <hip/hip_bf16.h>
#include <hip/hip_fp16.h>

#define N_NODES 50000
#define N_EDGES 1600000
#define IN_F 128
#define OUT_F 32
#define HEADS 4
#define NEG_SLOPE 0.2f
#define HO (HEADS * OUT_F)

#define NBUCKET 1563                           // ceil(N_NODES / 32)
#define BBLK 256                               // histogram/scatter blocks
#define EPB (N_EDGES / BBLK)                   // 6250 edges per block
#define PROJ_BLOCKS ((N_NODES + 63) / 64)      // 782
#define SCAN_BLKS ((NBUCKET + 255) / 256)      // 7
#define WPITCH 136                             // bf16 pitch (17 x b128)
#define BCAP 2048                              // max records per bucket (LDS)

typedef __attribute__((ext_vector_type(8))) short bf16x8;
typedef __attribute__((ext_vector_type(4))) float f32x4;

__device__ __forceinline__ unsigned short bf16_bits(float f) {
    union { __hip_bfloat16 b; unsigned short u; } cv;
    cv.b = __float2bfloat16(f);
    return cv.u;
}
__device__ __forceinline__ unsigned short f16_bits(float f) {
    union { __half h; unsigned short u; } cv;
    cv.h = __float2half(f);
    return cv.u;
}
__device__ __forceinline__ float f16u(unsigned short u) {
    union { unsigned short x; __half h; } cv;
    cv.x = u;
    return __half2float(cv.h);
}

// K1: blocks [0,256): per-block LDS histogram over 1563 coarse buckets
//     (dst>>5), coalesced dump. blocks [256,264): W -> Wtg bf16 transpose.
__global__ __launch_bounds__(256) void k_bhist(
    const int* __restrict__ ei, int* __restrict__ bhist,
    const float* __restrict__ W, unsigned short* __restrict__ Wtg)
{
    const int blk = blockIdx.x;
    const int t = threadIdx.x;
    if (blk >= BBLK) {                          // W prep
        const int bp = blk - BBLK;
        #pragma unroll
        for (int i = 0; i < 8; ++i) {
            const int idx = bp * 2048 + t + i * 256;   // 16384 f32 total
            const int h = idx >> 12;
            const int k = (idx >> 5) & 127;
            const int o = idx & 31;
            Wtg[(size_t)(h * 32 + o) * WPITCH + k] = bf16_bits(W[idx]);
        }
        return;
    }
    __shared__ int lhist[NBUCKET];
    for (int i = t; i < NBUCKET; i += 256) lhist[i] = 0;
    __syncthreads();
    const int* dstp = ei + N_EDGES + blk * EPB;
    for (int i = t; i < EPB; i += 256)
        atomicAdd(&lhist[dstp[i] >> 5], 1);
    __syncthreads();
    int* dump = bhist + (size_t)blk * NBUCKET;
    for (int i = t; i < NBUCKET; i += 256) dump[i] = lhist[i];
}

// K2: MFMA projection + fused attn dots; blocks >= PROJ_BLOCKS run the
//     bhist column-scan (hidden under the GEMM).
__global__ __launch_bounds__(256, 2) void k_proj_scan(
    const float* __restrict__ x, const unsigned short* __restrict__ Wtg,
    const float* __restrict__ a_src, const float* __restrict__ a_dst,
    unsigned short* __restrict__ h_u16, float* __restrict__ attn_s4,
    float* __restrict__ attn_d4, int* __restrict__ bhist,
    int* __restrict__ btotal)
{
    __shared__ unsigned short xls[64 * WPITCH];    // 17408 B
    __shared__ unsigned short wls[128 * WPITCH];   // 34816 B
    const int t = threadIdx.x;

    if (blockIdx.x >= PROJ_BLOCKS) {
        // ---- column exclusive scan of bhist over 256 block rows ----
        const int j = (blockIdx.x - PROJ_BLOCKS) * 256 + t;
        if (j >= NBUCKET) return;
        int run = 0;
        for (int blk = 0; blk < BBLK; blk += 8) {
            int v[8];
            #pragma unroll
            for (int q = 0; q < 8; ++q)
                v[q] = bhist[(size_t)(blk + q) * NBUCKET + j];
            #pragma unroll
            for (int q = 0; q < 8; ++q) {
                const int nv = v[q];
                bhist[(size_t)(blk + q) * NBUCKET + j] = run;
                run += nv;
            }
        }
        btotal[j] = run;
        return;
    }

    const int base = blockIdx.x * 64;
    {   // stage Wt (flat copy, already padded): 2176 uint4
        const uint4* src = (const uint4*)Wtg;
        uint4* dst = (uint4*)wls;
        for (int i = t; i < 2176; i += 256) dst[i] = src[i];
    }
    {   // stage x tile: 64 rows x 32 float4, convert to bf16
        const float4* xsrc = (const float4*)x + (size_t)base * 32;
        #pragma unroll
        for (int i = 0; i < 8; ++i) {
            const int idx = t + i * 256;           // 0..2047
            const int row = idx >> 5;
            const int c4 = idx & 31;
            float4 v = {0.f, 0.f, 0.f, 0.f};
            if (base + row < N_NODES) v = xsrc[row * 32 + c4];
            ushort4 o;
            o.x = bf16_bits(v.x); o.y = bf16_bits(v.y);
            o.z = bf16_bits(v.z); o.w = bf16_bits(v.w);
            *(ushort4*)&xls[row * WPITCH + c4 * 4] = o;
        }
    }
    __syncthreads();

    const int w = t >> 6;                          // m-tile 0..3
    const int lane = t & 63;
    const int lr = lane & 15;                      // A-row / B-col
    const int lq = lane >> 4;                      // k-quadrant

    const unsigned short* ap = &xls[(w * 16 + lr) * WPITCH + lq * 8];
    const unsigned short* bp = &wls[lr * WPITCH + lq * 8];

    f32x4 acc[8];
    #pragma unroll
    for (int ct = 0; ct < 8; ++ct) acc[ct] = (f32x4){0.f, 0.f, 0.f, 0.f};

    #pragma unroll
    for (int ks = 0; ks < 4; ++ks) {
        const bf16x8 a = *(const bf16x8*)(ap + ks * 32);
        #pragma unroll
        for (int ct = 0; ct < 8; ++ct) {
            const bf16x8 bv = *(const bf16x8*)(bp + ct * 16 * WPITCH + ks * 32);
            acc[ct] = __builtin_amdgcn_mfma_f32_16x16x32_bf16(a, bv, acc[ct], 0, 0, 0);
        }
    }

    const int nodeq = base + w * 16 + lq * 4;
    #pragma unroll
    for (int r = 0; r < 4; ++r) {
        const int node = nodeq + r;
        if (node >= N_NODES) continue;
        unsigned short* hrow = h_u16 + (size_t)node * 128 + lr;
        #pragma unroll
        for (int ct = 0; ct < 8; ++ct)
            hrow[ct * 16] = bf16_bits(acc[ct][r]);
    }

    float asv[8], adv[8];
    #pragma unroll
    for (int h = 0; h < 4; ++h) {
        asv[2 * h]     = a_src[32 * h + lr];
        asv[2 * h + 1] = a_src[32 * h + 16 + lr];
        adv[2 * h]     = a_dst[32 * h + lr];
        adv[2 * h + 1] = a_dst[32 * h + 16 + lr];
    }
    #pragma unroll
    for (int h = 0; h < 4; ++h) {
        #pragma unroll
        for (int r = 0; r < 4; ++r) {
            float ps = acc[2 * h][r] * asv[2 * h] + acc[2 * h + 1][r] * asv[2 * h + 1];
            float pd = acc[2 * h][r] * adv[2 * h] + acc[2 * h + 1][r] * adv[2 * h + 1];
            #pragma unroll
            for (int m = 8; m >= 1; m >>= 1) {
                ps += __shfl_xor(ps, m);
                pd += __shfl_xor(pd, m);
            }
            const int node = nodeq + r;
            if (lr == 0 && node < N_NODES) {
                attn_s4[node * HEADS + h] = ps;
                attn_d4[node * HEADS + h] = pd;
            }
        }
    }
}

// K3: exclusive scan of bucket totals -> bbase (single block)
__global__ __launch_bounds__(256) void k_bbase(
    const int* __restrict__ btotal, int* __restrict__ bbase)
{
    __shared__ int part[256];
    const int t = threadIdx.x;
    const int CH = 7;                              // 7*256 >= 1563
    const int lo = t * CH;
    const int hi = min(lo + CH, NBUCKET);
    int s = 0;
    for (int i = lo; i < hi; ++i) s += btotal[i];
    part[t] = s;
    __syncthreads();
    for (int d = 1; d < 256; d <<= 1) {
        const int v = (t >= d) ? part[t - d] : 0;
        __syncthreads();
        part[t] += v;
        __syncthreads();
    }
    int base = (t == 0) ? 0 : part[t - 1];
    for (int i = lo; i < hi; ++i) {
        bbase[i] = base;
        base += btotal[i];
    }
}

// K4: scatter edges into bucket-sorted order via LDS cursors.
// ONE 8 B record per edge: .x = (src16<<16)|f16(w), .y = dst & 31.
__global__ __launch_bounds__(256) void k_bscatter(
    const int* __restrict__ ei, const float* __restrict__ ew,
    const int* __restrict__ bhist, const int* __restrict__ bbase,
    uint2* __restrict__ brec64)
{
    __shared__ int cur[NBUCKET];
    const int blk = blockIdx.x;
    const int t = threadIdx.x;
    const int* row = bhist + (size_t)blk * NBUCKET;
    for (int i = t; i < NBUCKET; i += 256) cur[i] = bbase[i] + row[i];
    __syncthreads();
    const int* srcp = ei + blk * EPB;
    const int* dstp = ei + N_EDGES + blk * EPB;
    const float* wp = ew + blk * EPB;
    for (int i = t; i < EPB; i += 256) {
        const int src = srcp[i];
        const int dst = dstp[i];
        const float w = wp[i];
        const int pos = atomicAdd(&cur[dst >> 5], 1);
        brec64[pos] = make_uint2(((unsigned)src << 16) | (unsigned)f16_bits(w),
                                 (unsigned)(dst & 31));
    }
}

// K5: fused finish+aggregate. Block = one bucket (32 dsts).
// Pass 1 (global, L2-hot): 32-bin hist. Pass 2: sort records into LDS.
// Then lane-parallel aggregation per dst from LDS records.
__global__ __launch_bounds__(256) void k_aggfin(
    const uint2* __restrict__ brec64, const int* __restrict__ bbase,
    const int* __restrict__ btotal,
    const float* __restrict__ attn_s4, const float* __restrict__ attn_d4,
    const unsigned* __restrict__ h32, float* __restrict__ out)
{
    __shared__ unsigned srec[BCAP];
    __shared__ int bin[32], bcur[32], dstbeg[33];
    const int j = blockIdx.x;
    const int t = threadIdx.x;
    const int start = bbase[j];
    const int n = btotal[j];

    if (t < 32) bin[t] = 0;
    __syncthreads();
    for (int i = t; i < n; i += 256)
        atomicAdd(&bin[brec64[start + i].y], 1);
    __syncthreads();
    if (t == 0) {
        int run = 0;
        #pragma unroll
        for (int b = 0; b < 32; ++b) {
            dstbeg[b] = run; bcur[b] = run; run += bin[b];
        }
        dstbeg[32] = run;
    }
    __syncthreads();
    for (int i = t; i < n; i += 256) {
        const uint2 v = brec64[start + i];
        const int pos = atomicAdd(&bcur[v.y], 1);
        srec[pos] = v.x;
    }
    __syncthreads();

    // aggregation: wave wv handles local dsts [wv*8, wv*8+8)
    const int l = t & 63;
    const int le = l & 15;                         // edge slot
    const int lh = l >> 4;                         // head
    const int wv = t >> 6;
    const unsigned* hp = h32 + l;

    for (int d = wv * 8; d < wv * 8 + 8; ++d) {
        const int gdst = j * 32 + d;
        if (gdst >= N_NODES) break;
        const int beg = dstbeg[d];
        const int end = dstbeg[d + 1];
        const float ad = attn_d4[gdst * HEADS + lh];
        float den0 = 0.f, den1 = 0.f;
        float a0 = 0.f, a1 = 0.f, b0 = 0.f, b1 = 0.f;
        for (int c = beg; c < end; c += 16) {
            const int cnt = min(16, end - c);
            unsigned pk = 0;
            if (le < cnt) {
                const unsigned u = srec[c + le];
                const int s = u >> 16;
                float lo = attn_s4[s * HEADS + lh] + ad;
                lo = ((lo >= 0.f) ? lo : NEG_SLOPE * lo) * f16u(u & 0xffffu);
                pk = (u & 0xffff0000u) | (unsigned)f16_bits(__expf(lo));
            }
            if (cnt == 16) {
                #pragma unroll
                for (int q = 0; q < 16; q += 2) {
                    const unsigned k0 = (unsigned)__shfl((int)pk, q, 16);
                    const unsigned k1 = (unsigned)__shfl((int)pk, q + 1, 16);
                    const float p0 = f16u(k0 & 0xffffu);
                    const float p1 = f16u(k1 & 0xffffu);
                    const unsigned h0 = hp[(size_t)(k0 >> 16) * 64];
                    const unsigned h1 = hp[(size_t)(k1 >> 16) * 64];
                    a0 = fmaf(p0, __uint_as_float(h0 << 16), a0);
                    b0 = fmaf(p0, __uint_as_float(h0 & 0xffff0000u), b0);
                    a1 = fmaf(p1, __uint_as_float(h1 << 16), a1);
                    b1 = fmaf(p1, __uint_as_float(h1 & 0xffff0000u), b1);
                    den0 += p0;
                    den1 += p1;
                }
            } else {
                for (int q = 0; q < cnt; ++q) {
                    const unsigned k0 = (unsigned)__shfl((int)pk, q, 16);
                    const float p0 = f16u(k0 & 0xffffu);
                    const unsigned h0 = hp[(size_t)(k0 >> 16) * 64];
                    a0 = fmaf(p0, __uint_as_float(h0 << 16), a0);
                    b0 = fmaf(p0, __uint_as_float(h0 & 0xffff0000u), b0);
                    den0 += p0;
                }
            }
        }
        const float inv = 1.f / ((den0 + den1) + 1e-10f);
        float2 o;
        o.x = (a0 + a1) * inv;
        o.y = (b0 + b1) * inv;
        ((float2*)out)[(size_t)gdst * 64 + l] = o;
    }
}

extern "C" void kernel_launch(void* const* d_in, const int* in_sizes, int n_in,
                              void* d_out, int out_size, void* d_ws, size_t ws_size,
                              hipStream_t stream) {
    const float* x   = (const float*)d_in[0];
    const int*   ei  = (const int*)d_in[1];
    const float* ew  = (const float*)d_in[2];
    const float* W   = (const float*)d_in[3];
    const float* a_s = (const float*)d_in[4];
    const float* a_d = (const float*)d_in[5];
    float* out = (float*)d_out;

    unsigned* h32     = (unsigned*)d_ws;                          // 12.8 MB
    float*    attn_s4 = (float*)(h32 + (size_t)N_NODES * 64);     // 800 KB
    float*    attn_d4 = attn_s4 + (size_t)N_NODES * HEADS;        // 800 KB
    uint2*    brec64  = (uint2*)(attn_d4 + (size_t)N_NODES * HEADS); // 12.8 MB
    int*      bhist   = (int*)(brec64 + N_EDGES);                 // 1.6 MB
    int*      btotal  = bhist + BBLK * NBUCKET;                   // 6.3 KB
    int*      bbase   = btotal + NBUCKET;                         // 6.3 KB
    unsigned short* Wtg = (unsigned short*)(bbase + NBUCKET);     // 35 KB

    k_bhist<<<BBLK + 8, 256, 0, stream>>>(ei, bhist, W, Wtg);
    k_proj_scan<<<PROJ_BLOCKS + SCAN_BLKS, 256, 0, stream>>>(
        x, Wtg, a_s, a_d, (unsigned short*)h32, attn_s4, attn_d4,
        bhist, btotal);
    k_bbase<<<1, 256, 0, stream>>>(btotal, bbase);
    k_bscatter<<<BBLK, 256, 0, stream>>>(ei, ew, bhist, bbase, brec64);
    k_aggfin<<<NBUCKET, 256, 0, stream>>>(brec64, bbase, btotal,
                                          attn_s4, attn_d4, h32, out);
}

// Round 18
// 134.754 us; speedup vs baseline: 2.7220x; 1.1286x over previous
//
#include <hip/hip_runtime.h>
#include <hip/hip_bf16.h>
#include <hip/hip_fp16.h>

#define N_NODES 50000
#define N_EDGES 1600000
#define IN_F 128
#define OUT_F 32
#define HEADS 4
#define NEG_SLOPE 0.2f
#define HO (HEADS * OUT_F)

#define NBUCKET 1563                           // ceil(N_NODES / 32)
#define BBLK 256                               // histogram/scatter blocks
#define EPB (N_EDGES / BBLK)                   // 6250 edges per block
#define PROJ_BLOCKS ((N_NODES + 63) / 64)      // 782
#define SCAN_BLKS ((NBUCKET + 255) / 256)      // 7
#define AGG_BLOCKS 3125
#define AGG_WAVES (AGG_BLOCKS * 4)
#define WPITCH 136                             // bf16 pitch (17 x b128)
#define BCAP 2048                              // max records per bucket (LDS)

typedef __attribute__((ext_vector_type(8))) short bf16x8;
typedef __attribute__((ext_vector_type(4))) float f32x4;

__device__ __forceinline__ unsigned short bf16_bits(float f) {
    union { __hip_bfloat16 b; unsigned short u; } cv;
    cv.b = __float2bfloat16(f);
    return cv.u;
}
__device__ __forceinline__ unsigned short f16_bits(float f) {
    union { __half h; unsigned short u; } cv;
    cv.h = __float2half(f);
    return cv.u;
}
__device__ __forceinline__ float f16u(unsigned short u) {
    union { unsigned short x; __half h; } cv;
    cv.x = u;
    return __half2float(cv.h);
}

// K1: blocks [0,256): per-block LDS histogram over 1563 coarse buckets
//     (dst>>5), coalesced dump. blocks [256,264): W -> Wtg bf16 transpose.
__global__ __launch_bounds__(256) void k_bhist(
    const int* __restrict__ ei, int* __restrict__ bhist,
    const float* __restrict__ W, unsigned short* __restrict__ Wtg)
{
    const int blk = blockIdx.x;
    const int t = threadIdx.x;
    if (blk >= BBLK) {                          // W prep
        const int bp = blk - BBLK;
        #pragma unroll
        for (int i = 0; i < 8; ++i) {
            const int idx = bp * 2048 + t + i * 256;   // 16384 f32 total
            const int h = idx >> 12;
            const int k = (idx >> 5) & 127;
            const int o = idx & 31;
            Wtg[(size_t)(h * 32 + o) * WPITCH + k] = bf16_bits(W[idx]);
        }
        return;
    }
    __shared__ int lhist[NBUCKET];
    for (int i = t; i < NBUCKET; i += 256) lhist[i] = 0;
    __syncthreads();
    const int* dstp = ei + N_EDGES + blk * EPB;
    for (int i = t; i < EPB; i += 256)
        atomicAdd(&lhist[dstp[i] >> 5], 1);
    __syncthreads();
    int* dump = bhist + (size_t)blk * NBUCKET;
    for (int i = t; i < NBUCKET; i += 256) dump[i] = lhist[i];
}

// K2: MFMA projection + fused attn dots; blocks >= PROJ_BLOCKS run the
//     bhist column-scan (hidden under the GEMM).
__global__ __launch_bounds__(256, 2) void k_proj_scan(
    const float* __restrict__ x, const unsigned short* __restrict__ Wtg,
    const float* __restrict__ a_src, const float* __restrict__ a_dst,
    unsigned short* __restrict__ h_u16, float* __restrict__ attn_s4,
    float* __restrict__ attn_d4, int* __restrict__ bhist,
    int* __restrict__ btotal)
{
    __shared__ unsigned short xls[64 * WPITCH];    // 17408 B
    __shared__ unsigned short wls[128 * WPITCH];   // 34816 B
    const int t = threadIdx.x;

    if (blockIdx.x >= PROJ_BLOCKS) {
        const int j = (blockIdx.x - PROJ_BLOCKS) * 256 + t;
        if (j >= NBUCKET) return;
        int run = 0;
        for (int blk = 0; blk < BBLK; blk += 8) {
            int v[8];
            #pragma unroll
            for (int q = 0; q < 8; ++q)
                v[q] = bhist[(size_t)(blk + q) * NBUCKET + j];
            #pragma unroll
            for (int q = 0; q < 8; ++q) {
                const int nv = v[q];
                bhist[(size_t)(blk + q) * NBUCKET + j] = run;
                run += nv;
            }
        }
        btotal[j] = run;
        return;
    }

    const int base = blockIdx.x * 64;
    {   // stage Wt (flat copy, already padded): 2176 uint4
        const uint4* src = (const uint4*)Wtg;
        uint4* dst = (uint4*)wls;
        for (int i = t; i < 2176; i += 256) dst[i] = src[i];
    }
    {   // stage x tile: 64 rows x 32 float4, convert to bf16
        const float4* xsrc = (const float4*)x + (size_t)base * 32;
        #pragma unroll
        for (int i = 0; i < 8; ++i) {
            const int idx = t + i * 256;           // 0..2047
            const int row = idx >> 5;
            const int c4 = idx & 31;
            float4 v = {0.f, 0.f, 0.f, 0.f};
            if (base + row < N_NODES) v = xsrc[row * 32 + c4];
            ushort4 o;
            o.x = bf16_bits(v.x); o.y = bf16_bits(v.y);
            o.z = bf16_bits(v.z); o.w = bf16_bits(v.w);
            *(ushort4*)&xls[row * WPITCH + c4 * 4] = o;
        }
    }
    __syncthreads();

    const int w = t >> 6;                          // m-tile 0..3
    const int lane = t & 63;
    const int lr = lane & 15;                      // A-row / B-col
    const int lq = lane >> 4;                      // k-quadrant

    const unsigned short* ap = &xls[(w * 16 + lr) * WPITCH + lq * 8];
    const unsigned short* bp = &wls[lr * WPITCH + lq * 8];

    f32x4 acc[8];
    #pragma unroll
    for (int ct = 0; ct < 8; ++ct) acc[ct] = (f32x4){0.f, 0.f, 0.f, 0.f};

    #pragma unroll
    for (int ks = 0; ks < 4; ++ks) {
        const bf16x8 a = *(const bf16x8*)(ap + ks * 32);
        #pragma unroll
        for (int ct = 0; ct < 8; ++ct) {
            const bf16x8 bv = *(const bf16x8*)(bp + ct * 16 * WPITCH + ks * 32);
            acc[ct] = __builtin_amdgcn_mfma_f32_16x16x32_bf16(a, bv, acc[ct], 0, 0, 0);
        }
    }

    const int nodeq = base + w * 16 + lq * 4;
    #pragma unroll
    for (int r = 0; r < 4; ++r) {
        const int node = nodeq + r;
        if (node >= N_NODES) continue;
        unsigned short* hrow = h_u16 + (size_t)node * 128 + lr;
        #pragma unroll
        for (int ct = 0; ct < 8; ++ct)
            hrow[ct * 16] = bf16_bits(acc[ct][r]);
    }

    float asv[8], adv[8];
    #pragma unroll
    for (int h = 0; h < 4; ++h) {
        asv[2 * h]     = a_src[32 * h + lr];
        asv[2 * h + 1] = a_src[32 * h + 16 + lr];
        adv[2 * h]     = a_dst[32 * h + lr];
        adv[2 * h + 1] = a_dst[32 * h + 16 + lr];
    }
    #pragma unroll
    for (int h = 0; h < 4; ++h) {
        #pragma unroll
        for (int r = 0; r < 4; ++r) {
            float ps = acc[2 * h][r] * asv[2 * h] + acc[2 * h + 1][r] * asv[2 * h + 1];
            float pd = acc[2 * h][r] * adv[2 * h] + acc[2 * h + 1][r] * adv[2 * h + 1];
            #pragma unroll
            for (int m = 8; m >= 1; m >>= 1) {
                ps += __shfl_xor(ps, m);
                pd += __shfl_xor(pd, m);
            }
            const int node = nodeq + r;
            if (lr == 0 && node < N_NODES) {
                attn_s4[node * HEADS + h] = ps;
                attn_d4[node * HEADS + h] = pd;
            }
        }
    }
}

// K3: exclusive scan of bucket totals -> bbase (single block)
__global__ __launch_bounds__(256) void k_bbase(
    const int* __restrict__ btotal, int* __restrict__ bbase,
    int* __restrict__ offsets)
{
    __shared__ int part[256];
    const int t = threadIdx.x;
    const int CH = 7;                              // 7*256 >= 1563
    const int lo = t * CH;
    const int hi = min(lo + CH, NBUCKET);
    int s = 0;
    for (int i = lo; i < hi; ++i) s += btotal[i];
    part[t] = s;
    __syncthreads();
    for (int d = 1; d < 256; d <<= 1) {
        const int v = (t >= d) ? part[t - d] : 0;
        __syncthreads();
        part[t] += v;
        __syncthreads();
    }
    int base = (t == 0) ? 0 : part[t - 1];
    for (int i = lo; i < hi; ++i) {
        bbase[i] = base;
        base += btotal[i];
    }
    if (t == 0) offsets[N_NODES] = N_EDGES;
}

// K4: scatter edges into bucket-sorted order via LDS cursors.
// ONE 8 B record per edge: .x = (src16<<16)|f16(w), .y = dst & 31.
__global__ __launch_bounds__(256) void k_bscatter(
    const int* __restrict__ ei, const float* __restrict__ ew,
    const int* __restrict__ bhist, const int* __restrict__ bbase,
    uint2* __restrict__ brec64)
{
    __shared__ int cur[NBUCKET];
    const int blk = blockIdx.x;
    const int t = threadIdx.x;
    const int* row = bhist + (size_t)blk * NBUCKET;
    for (int i = t; i < NBUCKET; i += 256) cur[i] = bbase[i] + row[i];
    __syncthreads();
    const int* srcp = ei + blk * EPB;
    const int* dstp = ei + N_EDGES + blk * EPB;
    const float* wp = ew + blk * EPB;
    for (int i = t; i < EPB; i += 256) {
        const int src = srcp[i];
        const int dst = dstp[i];
        const float w = wp[i];
        const int pos = atomicAdd(&cur[dst >> 5], 1);
        brec64[pos] = make_uint2(((unsigned)src << 16) | (unsigned)f16_bits(w),
                                 (unsigned)(dst & 31));
    }
}

// K5: within-bucket finish, single global read. Bucket segment -> LDS,
// LDS hist+scan+sort, coalesced 4 B rec write + offsets.
__global__ __launch_bounds__(256) void k_bfinish(
    const uint2* __restrict__ brec64, const int* __restrict__ bbase,
    const int* __restrict__ btotal,
    unsigned* __restrict__ rec, int* __restrict__ offsets)
{
    __shared__ uint2 stage[BCAP];                  // 16 KB
    __shared__ unsigned sorted[BCAP];              // 8 KB
    __shared__ int bin[32], bcur[32];
    const int j = blockIdx.x;
    const int t = threadIdx.x;
    const int start = bbase[j];
    const int n = btotal[j];

    if (t < 32) bin[t] = 0;
    __syncthreads();
    for (int i = t; i < n; i += 256) {
        const uint2 v = brec64[start + i];
        stage[i] = v;
        atomicAdd(&bin[v.y], 1);
    }
    __syncthreads();
    if (t == 0) {
        int run = 0;
        #pragma unroll
        for (int b = 0; b < 32; ++b) { bcur[b] = run; run += bin[b]; }
    }
    __syncthreads();
    if (t < 32) {
        const int d = j * 32 + t;
        if (d < N_NODES) offsets[d] = start + bcur[t];
    }
    __syncthreads();
    for (int i = t; i < n; i += 256) {
        const uint2 v = stage[i];
        sorted[atomicAdd(&bcur[v.y], 1)] = v.x;
    }
    __syncthreads();
    for (int i = t; i < n; i += 256) rec[start + i] = sorted[i];
}

// K6: per-dst gather-aggregate (round-16, known 69 us). Lane-parallel
// p-phase; one shfl/edge; every lane holds full denominator.
__global__ __launch_bounds__(256) void k_aggregate(
    const unsigned* __restrict__ rec, const int* __restrict__ offsets,
    const float* __restrict__ attn_s4, const float* __restrict__ attn_d4,
    const unsigned* __restrict__ h32, float* __restrict__ out)
{
    const int l = threadIdx.x & 63;
    const int le = l & 15;                         // edge slot
    const int lh = l >> 4;                         // head
    const int wid = blockIdx.x * 4 + (threadIdx.x >> 6);
    const unsigned* hp = h32 + l;

    for (int dst = wid; dst < N_NODES; dst += AGG_WAVES) {
        const int beg = offsets[dst];
        const int end = offsets[dst + 1];
        const float ad = attn_d4[dst * HEADS + lh];
        float den0 = 0.f, den1 = 0.f;
        float a0 = 0.f, a1 = 0.f, b0 = 0.f, b1 = 0.f;
        for (int c = beg; c < end; c += 16) {
            const int cnt = min(16, end - c);
            unsigned pk = 0;
            if (le < cnt) {
                const unsigned u = rec[c + le];
                const int s = u >> 16;
                float lo = attn_s4[s * HEADS + lh] + ad;
                lo = ((lo >= 0.f) ? lo : NEG_SLOPE * lo) * f16u(u & 0xffffu);
                pk = (u & 0xffff0000u) | (unsigned)f16_bits(__expf(lo));
            }
            if (cnt == 16) {
                #pragma unroll
                for (int q = 0; q < 16; q += 2) {
                    const unsigned k0 = (unsigned)__shfl((int)pk, q, 16);
                    const unsigned k1 = (unsigned)__shfl((int)pk, q + 1, 16);
                    const float p0 = f16u(k0 & 0xffffu);
                    const float p1 = f16u(k1 & 0xffffu);
                    const unsigned h0 = hp[(size_t)(k0 >> 16) * 64];
                    const unsigned h1 = hp[(size_t)(k1 >> 16) * 64];
                    a0 = fmaf(p0, __uint_as_float(h0 << 16), a0);
                    b0 = fmaf(p0, __uint_as_float(h0 & 0xffff0000u), b0);
                    a1 = fmaf(p1, __uint_as_float(h1 << 16), a1);
                    b1 = fmaf(p1, __uint_as_float(h1 & 0xffff0000u), b1);
                    den0 += p0;
                    den1 += p1;
                }
            } else {
                for (int q = 0; q < cnt; ++q) {
                    const unsigned k0 = (unsigned)__shfl((int)pk, q, 16);
                    const float p0 = f16u(k0 & 0xffffu);
                    const unsigned h0 = hp[(size_t)(k0 >> 16) * 64];
                    a0 = fmaf(p0, __uint_as_float(h0 << 16), a0);
                    b0 = fmaf(p0, __uint_as_float(h0 & 0xffff0000u), b0);
                    den0 += p0;
                }
            }
        }
        const float inv = 1.f / ((den0 + den1) + 1e-10f);
        float2 o;
        o.x = (a0 + a1) * inv;
        o.y = (b0 + b1) * inv;
        ((float2*)out)[(size_t)dst * 64 + l] = o;
    }
}

extern "C" void kernel_launch(void* const* d_in, const int* in_sizes, int n_in,
                              void* d_out, int out_size, void* d_ws, size_t ws_size,
                              hipStream_t stream) {
    const float* x   = (const float*)d_in[0];
    const int*   ei  = (const int*)d_in[1];
    const float* ew  = (const float*)d_in[2];
    const float* W   = (const float*)d_in[3];
    const float* a_s = (const float*)d_in[4];
    const float* a_d = (const float*)d_in[5];
    float* out = (float*)d_out;

    unsigned* h32     = (unsigned*)d_ws;                          // 12.8 MB
    float*    attn_s4 = (float*)(h32 + (size_t)N_NODES * 64);     // 800 KB
    float*    attn_d4 = attn_s4 + (size_t)N_NODES * HEADS;        // 800 KB
    uint2*    brec64  = (uint2*)(attn_d4 + (size_t)N_NODES * HEADS); // 12.8 MB
    unsigned* rec     = (unsigned*)(brec64 + N_EDGES);            // 6.4 MB
    int*      bhist   = (int*)(rec + N_EDGES);                    // 1.6 MB
    int*      btotal  = bhist + BBLK * NBUCKET;                   // 6.3 KB
    int*      bbase   = btotal + NBUCKET;                         // 6.3 KB
    int*      offsets = bbase + NBUCKET;                          // 200 KB
    unsigned short* Wtg = (unsigned short*)(offsets + N_NODES + 1); // 35 KB

    k_bhist<<<BBLK + 8, 256, 0, stream>>>(ei, bhist, W, Wtg);
    k_proj_scan<<<PROJ_BLOCKS + SCAN_BLKS, 256, 0, stream>>>(
        x, Wtg, a_s, a_d, (unsigned short*)h32, attn_s4, attn_d4,
        bhist, btotal);
    k_bbase<<<1, 256, 0, stream>>>(btotal, bbase, offsets);
    k_bscatter<<<BBLK, 256, 0, stream>>>(ei, ew, bhist, bbase, brec64);
    k_bfinish<<<NBUCKET, 256, 0, stream>>>(brec64, bbase, btotal, rec, offsets);
    k_aggregate<<<AGG_BLOCKS, 256, 0, stream>>>(rec, offsets, attn_s4,
                                                attn_d4, h32, out);
}

// Round 19
// 132.202 us; speedup vs baseline: 2.7745x; 1.0193x over previous
//
#include <hip/hip_runtime.h>
#include <hip/hip_bf16.h>
#include <hip/hip_fp16.h>

#define N_NODES 50000
#define N_EDGES 1600000
#define IN_F 128
#define OUT_F 32
#define HEADS 4
#define NEG_SLOPE 0.2f
#define HO (HEADS * OUT_F)

#define NBUCKET 1563                           // ceil(N_NODES / 32)
#define BBLK 256                               // histogram/scatter blocks
#define EPB (N_EDGES / BBLK)                   // 6250 edges per block
#define PROJ_BLOCKS ((N_NODES + 63) / 64)      // 782
#define PROJ_A 391                             // first-half proj blocks
#define PROJ_B (PROJ_BLOCKS - PROJ_A)          // 391
#define SCAN_BLKS ((NBUCKET + 255) / 256)      // 7
#define AGG_BLOCKS 3125
#define AGG_WAVES (AGG_BLOCKS * 4)
#define WPITCH 136                             // bf16 pitch (17 x b128)
#define BCAP 2048                              // max records per bucket (LDS)

typedef __attribute__((ext_vector_type(8))) short bf16x8;
typedef __attribute__((ext_vector_type(4))) float f32x4;

__device__ __forceinline__ unsigned short bf16_bits(float f) {
    union { __hip_bfloat16 b; unsigned short u; } cv;
    cv.b = __float2bfloat16(f);
    return cv.u;
}
__device__ __forceinline__ unsigned short f16_bits(float f) {
    union { __half h; unsigned short u; } cv;
    cv.h = __float2half(f);
    return cv.u;
}
__device__ __forceinline__ float f16u(unsigned short u) {
    union { unsigned short x; __half h; } cv;
    cv.x = u;
    return __half2float(cv.h);
}

// ---- shared proj body (node tile pb: 64 nodes x 128 cols, K=128) ----
__device__ __forceinline__ void proj_body(
    int pb, int t, unsigned short* xls, unsigned short* wls,
    const float* __restrict__ x, const unsigned short* __restrict__ Wtg,
    const float* __restrict__ a_src, const float* __restrict__ a_dst,
    unsigned short* __restrict__ h_u16, float* __restrict__ attn_s4,
    float* __restrict__ attn_d4)
{
    const int base = pb * 64;
    {   // stage Wt (flat copy, already padded): 2176 uint4
        const uint4* src = (const uint4*)Wtg;
        uint4* dst = (uint4*)wls;
        for (int i = t; i < 2176; i += 256) dst[i] = src[i];
    }
    {   // stage x tile: 64 rows x 32 float4, convert to bf16
        const float4* xsrc = (const float4*)x + (size_t)base * 32;
        #pragma unroll
        for (int i = 0; i < 8; ++i) {
            const int idx = t + i * 256;           // 0..2047
            const int row = idx >> 5;
            const int c4 = idx & 31;
            float4 v = {0.f, 0.f, 0.f, 0.f};
            if (base + row < N_NODES) v = xsrc[row * 32 + c4];
            ushort4 o;
            o.x = bf16_bits(v.x); o.y = bf16_bits(v.y);
            o.z = bf16_bits(v.z); o.w = bf16_bits(v.w);
            *(ushort4*)&xls[row * WPITCH + c4 * 4] = o;
        }
    }
    __syncthreads();

    const int w = t >> 6;                          // m-tile 0..3
    const int lane = t & 63;
    const int lr = lane & 15;                      // A-row / B-col
    const int lq = lane >> 4;                      // k-quadrant

    const unsigned short* ap = &xls[(w * 16 + lr) * WPITCH + lq * 8];
    const unsigned short* bp = &wls[lr * WPITCH + lq * 8];

    f32x4 acc[8];
    #pragma unroll
    for (int ct = 0; ct < 8; ++ct) acc[ct] = (f32x4){0.f, 0.f, 0.f, 0.f};

    #pragma unroll
    for (int ks = 0; ks < 4; ++ks) {
        const bf16x8 a = *(const bf16x8*)(ap + ks * 32);
        #pragma unroll
        for (int ct = 0; ct < 8; ++ct) {
            const bf16x8 bv = *(const bf16x8*)(bp + ct * 16 * WPITCH + ks * 32);
            acc[ct] = __builtin_amdgcn_mfma_f32_16x16x32_bf16(a, bv, acc[ct], 0, 0, 0);
        }
    }

    const int nodeq = base + w * 16 + lq * 4;
    #pragma unroll
    for (int r = 0; r < 4; ++r) {
        const int node = nodeq + r;
        if (node >= N_NODES) continue;
        unsigned short* hrow = h_u16 + (size_t)node * 128 + lr;
        #pragma unroll
        for (int ct = 0; ct < 8; ++ct)
            hrow[ct * 16] = bf16_bits(acc[ct][r]);
    }

    float asv[8], adv[8];
    #pragma unroll
    for (int h = 0; h < 4; ++h) {
        asv[2 * h]     = a_src[32 * h + lr];
        asv[2 * h + 1] = a_src[32 * h + 16 + lr];
        adv[2 * h]     = a_dst[32 * h + lr];
        adv[2 * h + 1] = a_dst[32 * h + 16 + lr];
    }
    #pragma unroll
    for (int h = 0; h < 4; ++h) {
        #pragma unroll
        for (int r = 0; r < 4; ++r) {
            float ps = acc[2 * h][r] * asv[2 * h] + acc[2 * h + 1][r] * asv[2 * h + 1];
            float pd = acc[2 * h][r] * adv[2 * h] + acc[2 * h + 1][r] * adv[2 * h + 1];
            #pragma unroll
            for (int m = 8; m >= 1; m >>= 1) {
                ps += __shfl_xor(ps, m);
                pd += __shfl_xor(pd, m);
            }
            const int node = nodeq + r;
            if (lr == 0 && node < N_NODES) {
                attn_s4[node * HEADS + h] = ps;
                attn_d4[node * HEADS + h] = pd;
            }
        }
    }
}

// K1: blocks [0,256): per-block LDS histogram over 1563 coarse buckets
//     (dst>>5), coalesced dump. blocks [256,264): W -> Wtg bf16 transpose.
__global__ __launch_bounds__(256) void k_bhist(
    const int* __restrict__ ei, int* __restrict__ bhist,
    const float* __restrict__ W, unsigned short* __restrict__ Wtg)
{
    const int blk = blockIdx.x;
    const int t = threadIdx.x;
    if (blk >= BBLK) {                          // W prep
        const int bp = blk - BBLK;
        #pragma unroll
        for (int i = 0; i < 8; ++i) {
            const int idx = bp * 2048 + t + i * 256;   // 16384 f32 total
            const int h = idx >> 12;
            const int k = (idx >> 5) & 127;
            const int o = idx & 31;
            Wtg[(size_t)(h * 32 + o) * WPITCH + k] = bf16_bits(W[idx]);
        }
        return;
    }
    __shared__ int lhist[NBUCKET];
    for (int i = t; i < NBUCKET; i += 256) lhist[i] = 0;
    __syncthreads();
    const int* dstp = ei + N_EDGES + blk * EPB;
    for (int i = t; i < EPB; i += 256)
        atomicAdd(&lhist[dstp[i] >> 5], 1);
    __syncthreads();
    int* dump = bhist + (size_t)blk * NBUCKET;
    for (int i = t; i < NBUCKET; i += 256) dump[i] = lhist[i];
}

// K2: proj first half (nodes [0, 391*64)) ∥ bhist column-scan.
__global__ __launch_bounds__(256, 2) void k_projA_scan(
    const float* __restrict__ x, const unsigned short* __restrict__ Wtg,
    const float* __restrict__ a_src, const float* __restrict__ a_dst,
    unsigned short* __restrict__ h_u16, float* __restrict__ attn_s4,
    float* __restrict__ attn_d4, int* __restrict__ bhist,
    int* __restrict__ btotal)
{
    __shared__ unsigned short xls[64 * WPITCH];    // 17408 B
    __shared__ unsigned short wls[128 * WPITCH];   // 34816 B
    const int t = threadIdx.x;

    if (blockIdx.x < SCAN_BLKS) {
        const int j = blockIdx.x * 256 + t;
        if (j >= NBUCKET) return;
        int run = 0;
        for (int blk = 0; blk < BBLK; blk += 8) {
            int v[8];
            #pragma unroll
            for (int q = 0; q < 8; ++q)
                v[q] = bhist[(size_t)(blk + q) * NBUCKET + j];
            #pragma unroll
            for (int q = 0; q < 8; ++q) {
                const int nv = v[q];
                bhist[(size_t)(blk + q) * NBUCKET + j] = run;
                run += nv;
            }
        }
        btotal[j] = run;
        return;
    }
    proj_body(blockIdx.x - SCAN_BLKS, t, xls, wls,
              x, Wtg, a_src, a_dst, h_u16, attn_s4, attn_d4);
}

// K3: exclusive scan of bucket totals -> bbase (single block)
__global__ __launch_bounds__(256) void k_bbase(
    const int* __restrict__ btotal, int* __restrict__ bbase,
    int* __restrict__ offsets)
{
    __shared__ int part[256];
    const int t = threadIdx.x;
    const int CH = 7;                              // 7*256 >= 1563
    const int lo = t * CH;
    const int hi = min(lo + CH, NBUCKET);
    int s = 0;
    for (int i = lo; i < hi; ++i) s += btotal[i];
    part[t] = s;
    __syncthreads();
    for (int d = 1; d < 256; d <<= 1) {
        const int v = (t >= d) ? part[t - d] : 0;
        __syncthreads();
        part[t] += v;
        __syncthreads();
    }
    int base = (t == 0) ? 0 : part[t - 1];
    for (int i = lo; i < hi; ++i) {
        bbase[i] = base;
        base += btotal[i];
    }
    if (t == 0) offsets[N_NODES] = N_EDGES;
}

// K4: bscatter (blocks [0,256), starts first) ∥ proj second half.
__global__ __launch_bounds__(256, 2) void k_projB_scatter(
    const float* __restrict__ x, const unsigned short* __restrict__ Wtg,
    const float* __restrict__ a_src, const float* __restrict__ a_dst,
    unsigned short* __restrict__ h_u16, float* __restrict__ attn_s4,
    float* __restrict__ attn_d4,
    const int* __restrict__ ei, const float* __restrict__ ew,
    const int* __restrict__ bhist, const int* __restrict__ bbase,
    uint2* __restrict__ brec64)
{
    __shared__ unsigned short xls[64 * WPITCH];    // 17408 B
    __shared__ unsigned short wls[128 * WPITCH];   // 34816 B
    __shared__ int cur[NBUCKET];                   // 6252 B
    const int t = threadIdx.x;

    if (blockIdx.x < BBLK) {
        // ---- scatter half ----
        const int blk = blockIdx.x;
        const int* row = bhist + (size_t)blk * NBUCKET;
        for (int i = t; i < NBUCKET; i += 256) cur[i] = bbase[i] + row[i];
        __syncthreads();
        const int* srcp = ei + blk * EPB;
        const int* dstp = ei + N_EDGES + blk * EPB;
        const float* wp = ew + blk * EPB;
        for (int i = t; i < EPB; i += 256) {
            const int src = srcp[i];
            const int dst = dstp[i];
            const float w = wp[i];
            const int pos = atomicAdd(&cur[dst >> 5], 1);
            brec64[pos] = make_uint2(((unsigned)src << 16) | (unsigned)f16_bits(w),
                                     (unsigned)(dst & 31));
        }
        return;
    }
    proj_body(blockIdx.x - BBLK + PROJ_A, t, xls, wls,
              x, Wtg, a_src, a_dst, h_u16, attn_s4, attn_d4);
}

// K5: within-bucket finish, single global read. Bucket segment -> LDS,
// LDS hist+scan+sort, coalesced 4 B rec write + offsets.
__global__ __launch_bounds__(256) void k_bfinish(
    const uint2* __restrict__ brec64, const int* __restrict__ bbase,
    const int* __restrict__ btotal,
    unsigned* __restrict__ rec, int* __restrict__ offsets)
{
    __shared__ uint2 stage[BCAP];                  // 16 KB
    __shared__ unsigned sorted[BCAP];              // 8 KB
    __shared__ int bin[32], bcur[32];
    const int j = blockIdx.x;
    const int t = threadIdx.x;
    const int start = bbase[j];
    const int n = btotal[j];

    if (t < 32) bin[t] = 0;
    __syncthreads();
    for (int i = t; i < n; i += 256) {
        const uint2 v = brec64[start + i];
        stage[i] = v;
        atomicAdd(&bin[v.y], 1);
    }
    __syncthreads();
    if (t == 0) {
        int run = 0;
        #pragma unroll
        for (int b = 0; b < 32; ++b) { bcur[b] = run; run += bin[b]; }
    }
    __syncthreads();
    if (t < 32) {
        const int d = j * 32 + t;
        if (d < N_NODES) offsets[d] = start + bcur[t];
    }
    __syncthreads();
    for (int i = t; i < n; i += 256) {
        const uint2 v = stage[i];
        sorted[atomicAdd(&bcur[v.y], 1)] = v.x;
    }
    __syncthreads();
    for (int i = t; i < n; i += 256) rec[start + i] = sorted[i];
}

// K6: per-dst gather-aggregate (known 69 us). Lane-parallel p-phase;
// one shfl/edge; every lane holds full denominator.
__global__ __launch_bounds__(256) void k_aggregate(
    const unsigned* __restrict__ rec, const int* __restrict__ offsets,
    const float* __restrict__ attn_s4, const float* __restrict__ attn_d4,
    const unsigned* __restrict__ h32, float* __restrict__ out)
{
    const int l = threadIdx.x & 63;
    const int le = l & 15;                         // edge slot
    const int lh = l >> 4;                         // head
    const int wid = blockIdx.x * 4 + (threadIdx.x >> 6);
    const unsigned* hp = h32 + l;

    for (int dst = wid; dst < N_NODES; dst += AGG_WAVES) {
        const int beg = offsets[dst];
        const int end = offsets[dst + 1];
        const float ad = attn_d4[dst * HEADS + lh];
        float den0 = 0.f, den1 = 0.f;
        float a0 = 0.f, a1 = 0.f, b0 = 0.f, b1 = 0.f;
        for (int c = beg; c < end; c += 16) {
            const int cnt = min(16, end - c);
            unsigned pk = 0;
            if (le < cnt) {
                const unsigned u = rec[c + le];
                const int s = u >> 16;
                float lo = attn_s4[s * HEADS + lh] + ad;
                lo = ((lo >= 0.f) ? lo : NEG_SLOPE * lo) * f16u(u & 0xffffu);
                pk = (u & 0xffff0000u) | (unsigned)f16_bits(__expf(lo));
            }
            if (cnt == 16) {
                #pragma unroll
                for (int q = 0; q < 16; q += 2) {
                    const unsigned k0 = (unsigned)__shfl((int)pk, q, 16);
                    const unsigned k1 = (unsigned)__shfl((int)pk, q + 1, 16);
                    const float p0 = f16u(k0 & 0xffffu);
                    const float p1 = f16u(k1 & 0xffffu);
                    const unsigned h0 = hp[(size_t)(k0 >> 16) * 64];
                    const unsigned h1 = hp[(size_t)(k1 >> 16) * 64];
                    a0 = fmaf(p0, __uint_as_float(h0 << 16), a0);
                    b0 = fmaf(p0, __uint_as_float(h0 & 0xffff0000u), b0);
                    a1 = fmaf(p1, __uint_as_float(h1 << 16), a1);
                    b1 = fmaf(p1, __uint_as_float(h1 & 0xffff0000u), b1);
                    den0 += p0;
                    den1 += p1;
                }
            } else {
                for (int q = 0; q < cnt; ++q) {
                    const unsigned k0 = (unsigned)__shfl((int)pk, q, 16);
                    const float p0 = f16u(k0 & 0xffffu);
                    const unsigned h0 = hp[(size_t)(k0 >> 16) * 64];
                    a0 = fmaf(p0, __uint_as_float(h0 << 16), a0);
                    b0 = fmaf(p0, __uint_as_float(h0 & 0xffff0000u), b0);
                    den0 += p0;
                }
            }
        }
        const float inv = 1.f / ((den0 + den1) + 1e-10f);
        float2 o;
        o.x = (a0 + a1) * inv;
        o.y = (b0 + b1) * inv;
        ((float2*)out)[(size_t)dst * 64 + l] = o;
    }
}

extern "C" void kernel_launch(void* const* d_in, const int* in_sizes, int n_in,
                              void* d_out, int out_size, void* d_ws, size_t ws_size,
                              hipStream_t stream) {
    const float* x   = (const float*)d_in[0];
    const int*   ei  = (const int*)d_in[1];
    const float* ew  = (const float*)d_in[2];
    const float* W   = (const float*)d_in[3];
    const float* a_s = (const float*)d_in[4];
    const float* a_d = (const float*)d_in[5];
    float* out = (float*)d_out;

    unsigned* h32     = (unsigned*)d_ws;                          // 12.8 MB
    float*    attn_s4 = (float*)(h32 + (size_t)N_NODES * 64);     // 800 KB
    float*    attn_d4 = attn_s4 + (size_t)N_NODES * HEADS;        // 800 KB
    uint2*    brec64  = (uint2*)(attn_d4 + (size_t)N_NODES * HEADS); // 12.8 MB
    unsigned* rec     = (unsigned*)(brec64 + N_EDGES);            // 6.4 MB
    int*      bhist   = (int*)(rec + N_EDGES);                    // 1.6 MB
    int*      btotal  = bhist + BBLK * NBUCKET;                   // 6.3 KB
    int*      bbase   = btotal + NBUCKET;                         // 6.3 KB
    int*      offsets = bbase + NBUCKET;                          // 200 KB
    unsigned short* Wtg = (unsigned short*)(offsets + N_NODES + 1); // 35 KB

    k_bhist<<<BBLK + 8, 256, 0, stream>>>(ei, bhist, W, Wtg);
    k_projA_scan<<<SCAN_BLKS + PROJ_A, 256, 0, stream>>>(
        x, Wtg, a_s, a_d, (unsigned short*)h32, attn_s4, attn_d4,
        bhist, btotal);
    k_bbase<<<1, 256, 0, stream>>>(btotal, bbase, offsets);
    k_projB_scatter<<<BBLK + PROJ_B, 256, 0, stream>>>(
        x, Wtg, a_s, a_d, (unsigned short*)h32, attn_s4, attn_d4,
        ei, ew, bhist, bbase, brec64);
    k_bfinish<<<NBUCKET, 256, 0, stream>>>(brec64, bbase, btotal, rec, offsets);
    k_aggregate<<<AGG_BLOCKS, 256, 0, stream>>>(rec, offsets, attn_s4,
                                                attn_d4, h32, out);
}

// Round 20
// 128.896 us; speedup vs baseline: 2.8457x; 1.0256x over previous
//
#include <hip/hip_runtime.h>
#include <hip/hip_bf16.h>
#include <hip/hip_fp16.h>

#define N_NODES 50000
#define N_EDGES 1600000
#define IN_F 128
#define OUT_F 32
#define HEADS 4
#define NEG_SLOPE 0.2f
#define HO (HEADS * OUT_F)

#define NBUCKET 1563                           // ceil(N_NODES / 32)
#define BBLK 256                               // histogram/scatter blocks
#define EPB (N_EDGES / BBLK)                   // 6250 edges per block
#define PROJ_BLOCKS ((N_NODES + 63) / 64)      // 782
#define PROJ_A 391                             // first-half proj blocks
#define PROJ_B (PROJ_BLOCKS - PROJ_A)          // 391
#define SCAN_BLKS ((NBUCKET + 255) / 256)      // 7
#define AGG_BLOCKS 3125
#define AGG_WAVES (AGG_BLOCKS * 4)
#define WPITCH 136                             // bf16 pitch (17 x b128)
#define BCAP 2048                              // max records per bucket (LDS)

typedef __attribute__((ext_vector_type(8))) short bf16x8;
typedef __attribute__((ext_vector_type(4))) float f32x4;

__device__ __forceinline__ unsigned short bf16_bits(float f) {
    union { __hip_bfloat16 b; unsigned short u; } cv;
    cv.b = __float2bfloat16(f);
    return cv.u;
}
__device__ __forceinline__ unsigned short f16_bits(float f) {
    union { __half h; unsigned short u; } cv;
    cv.h = __float2half(f);
    return cv.u;
}
__device__ __forceinline__ float f16u(unsigned short u) {
    union { unsigned short x; __half h; } cv;
    cv.x = u;
    return __half2float(cv.h);
}

// ---- shared proj body (node tile pb: 64 nodes x 128 cols, K=128) ----
__device__ __forceinline__ void proj_body(
    int pb, int t, unsigned short* xls, unsigned short* wls,
    const float* __restrict__ x, const unsigned short* __restrict__ Wtg,
    const float* __restrict__ a_src, const float* __restrict__ a_dst,
    unsigned short* __restrict__ h_u16, float* __restrict__ attn_s4,
    float* __restrict__ attn_d4)
{
    const int base = pb * 64;
    {   // stage Wt (flat copy, already padded): 2176 uint4
        const uint4* src = (const uint4*)Wtg;
        uint4* dst = (uint4*)wls;
        for (int i = t; i < 2176; i += 256) dst[i] = src[i];
    }
    {   // stage x tile: 64 rows x 32 float4, convert to bf16
        const float4* xsrc = (const float4*)x + (size_t)base * 32;
        #pragma unroll
        for (int i = 0; i < 8; ++i) {
            const int idx = t + i * 256;           // 0..2047
            const int row = idx >> 5;
            const int c4 = idx & 31;
            float4 v = {0.f, 0.f, 0.f, 0.f};
            if (base + row < N_NODES) v = xsrc[row * 32 + c4];
            ushort4 o;
            o.x = bf16_bits(v.x); o.y = bf16_bits(v.y);
            o.z = bf16_bits(v.z); o.w = bf16_bits(v.w);
            *(ushort4*)&xls[row * WPITCH + c4 * 4] = o;
        }
    }
    __syncthreads();

    const int w = t >> 6;                          // m-tile 0..3
    const int lane = t & 63;
    const int lr = lane & 15;                      // A-row / B-col
    const int lq = lane >> 4;                      // k-quadrant

    const unsigned short* ap = &xls[(w * 16 + lr) * WPITCH + lq * 8];
    const unsigned short* bp = &wls[lr * WPITCH + lq * 8];

    f32x4 acc[8];
    #pragma unroll
    for (int ct = 0; ct < 8; ++ct) acc[ct] = (f32x4){0.f, 0.f, 0.f, 0.f};

    #pragma unroll
    for (int ks = 0; ks < 4; ++ks) {
        const bf16x8 a = *(const bf16x8*)(ap + ks * 32);
        #pragma unroll
        for (int ct = 0; ct < 8; ++ct) {
            const bf16x8 bv = *(const bf16x8*)(bp + ct * 16 * WPITCH + ks * 32);
            acc[ct] = __builtin_amdgcn_mfma_f32_16x16x32_bf16(a, bv, acc[ct], 0, 0, 0);
        }
    }

    const int nodeq = base + w * 16 + lq * 4;
    #pragma unroll
    for (int r = 0; r < 4; ++r) {
        const int node = nodeq + r;
        if (node >= N_NODES) continue;
        unsigned short* hrow = h_u16 + (size_t)node * 128 + lr;
        #pragma unroll
        for (int ct = 0; ct < 8; ++ct)
            hrow[ct * 16] = bf16_bits(acc[ct][r]);
    }

    float asv[8], adv[8];
    #pragma unroll
    for (int h = 0; h < 4; ++h) {
        asv[2 * h]     = a_src[32 * h + lr];
        asv[2 * h + 1] = a_src[32 * h + 16 + lr];
        adv[2 * h]     = a_dst[32 * h + lr];
        adv[2 * h + 1] = a_dst[32 * h + 16 + lr];
    }
    #pragma unroll
    for (int h = 0; h < 4; ++h) {
        #pragma unroll
        for (int r = 0; r < 4; ++r) {
            float ps = acc[2 * h][r] * asv[2 * h] + acc[2 * h + 1][r] * asv[2 * h + 1];
            float pd = acc[2 * h][r] * adv[2 * h] + acc[2 * h + 1][r] * adv[2 * h + 1];
            #pragma unroll
            for (int m = 8; m >= 1; m >>= 1) {
                ps += __shfl_xor(ps, m);
                pd += __shfl_xor(pd, m);
            }
            const int node = nodeq + r;
            if (lr == 0 && node < N_NODES) {
                attn_s4[node * HEADS + h] = ps;
                attn_d4[node * HEADS + h] = pd;
            }
        }
    }
}

// K1: blocks [0,256): per-block LDS histogram over 1563 coarse buckets
//     (dst>>5). 1024 threads/block (was 256: 12.5% occupancy, latency-bound).
//     blocks [256,264): W -> Wtg bf16 transpose.
__global__ __launch_bounds__(1024) void k_bhist(
    const int* __restrict__ ei, int* __restrict__ bhist,
    const float* __restrict__ W, unsigned short* __restrict__ Wtg)
{
    const int blk = blockIdx.x;
    const int t = threadIdx.x;
    if (blk >= BBLK) {                          // W prep
        const int bp = blk - BBLK;
        #pragma unroll
        for (int i = 0; i < 2; ++i) {
            const int idx = bp * 2048 + t + i * 1024;  // 16384 f32 total
            const int h = idx >> 12;
            const int k = (idx >> 5) & 127;
            const int o = idx & 31;
            Wtg[(size_t)(h * 32 + o) * WPITCH + k] = bf16_bits(W[idx]);
        }
        return;
    }
    __shared__ int lhist[NBUCKET];
    for (int i = t; i < NBUCKET; i += 1024) lhist[i] = 0;
    __syncthreads();
    const int* dstp = ei + N_EDGES + blk * EPB;
    for (int i = t; i < EPB; i += 1024)
        atomicAdd(&lhist[dstp[i] >> 5], 1);
    __syncthreads();
    int* dump = bhist + (size_t)blk * NBUCKET;
    for (int i = t; i < NBUCKET; i += 1024) dump[i] = lhist[i];
}

// K2: proj first half (nodes [0, 391*64)) ∥ bhist column-scan.
__global__ __launch_bounds__(256, 2) void k_projA_scan(
    const float* __restrict__ x, const unsigned short* __restrict__ Wtg,
    const float* __restrict__ a_src, const float* __restrict__ a_dst,
    unsigned short* __restrict__ h_u16, float* __restrict__ attn_s4,
    float* __restrict__ attn_d4, int* __restrict__ bhist,
    int* __restrict__ btotal)
{
    __shared__ unsigned short xls[64 * WPITCH];    // 17408 B
    __shared__ unsigned short wls[128 * WPITCH];   // 34816 B
    const int t = threadIdx.x;

    if (blockIdx.x < SCAN_BLKS) {
        const int j = blockIdx.x * 256 + t;
        if (j >= NBUCKET) return;
        int run = 0;
        for (int blk = 0; blk < BBLK; blk += 8) {
            int v[8];
            #pragma unroll
            for (int q = 0; q < 8; ++q)
                v[q] = bhist[(size_t)(blk + q) * NBUCKET + j];
            #pragma unroll
            for (int q = 0; q < 8; ++q) {
                const int nv = v[q];
                bhist[(size_t)(blk + q) * NBUCKET + j] = run;
                run += nv;
            }
        }
        btotal[j] = run;
        return;
    }
    proj_body(blockIdx.x - SCAN_BLKS, t, xls, wls,
              x, Wtg, a_src, a_dst, h_u16, attn_s4, attn_d4);
}

// K3: exclusive scan of bucket totals -> bbase (single block)
__global__ __launch_bounds__(256) void k_bbase(
    const int* __restrict__ btotal, int* __restrict__ bbase,
    int* __restrict__ offsets)
{
    __shared__ int part[256];
    const int t = threadIdx.x;
    const int CH = 7;                              // 7*256 >= 1563
    const int lo = t * CH;
    const int hi = min(lo + CH, NBUCKET);
    int s = 0;
    for (int i = lo; i < hi; ++i) s += btotal[i];
    part[t] = s;
    __syncthreads();
    for (int d = 1; d < 256; d <<= 1) {
        const int v = (t >= d) ? part[t - d] : 0;
        __syncthreads();
        part[t] += v;
        __syncthreads();
    }
    int base = (t == 0) ? 0 : part[t - 1];
    for (int i = lo; i < hi; ++i) {
        bbase[i] = base;
        base += btotal[i];
    }
    if (t == 0) offsets[N_NODES] = N_EDGES;
}

// K4: bscatter (blocks [0,256), starts first) ∥ proj second half.
__global__ __launch_bounds__(256, 2) void k_projB_scatter(
    const float* __restrict__ x, const unsigned short* __restrict__ Wtg,
    const float* __restrict__ a_src, const float* __restrict__ a_dst,
    unsigned short* __restrict__ h_u16, float* __restrict__ attn_s4,
    float* __restrict__ attn_d4,
    const int* __restrict__ ei, const float* __restrict__ ew,
    const int* __restrict__ bhist, const int* __restrict__ bbase,
    uint2* __restrict__ brec64)
{
    __shared__ unsigned short xls[64 * WPITCH];    // 17408 B
    __shared__ unsigned short wls[128 * WPITCH];   // 34816 B
    __shared__ int cur[NBUCKET];                   // 6252 B
    const int t = threadIdx.x;

    if (blockIdx.x < BBLK) {
        // ---- scatter half ----
        const int blk = blockIdx.x;
        const int* row = bhist + (size_t)blk * NBUCKET;
        for (int i = t; i < NBUCKET; i += 256) cur[i] = bbase[i] + row[i];
        __syncthreads();
        const int* srcp = ei + blk * EPB;
        const int* dstp = ei + N_EDGES + blk * EPB;
        const float* wp = ew + blk * EPB;
        for (int i = t; i < EPB; i += 256) {
            const int src = srcp[i];
            const int dst = dstp[i];
            const float w = wp[i];
            const int pos = atomicAdd(&cur[dst >> 5], 1);
            brec64[pos] = make_uint2(((unsigned)src << 16) | (unsigned)f16_bits(w),
                                     (unsigned)(dst & 31));
        }
        return;
    }
    proj_body(blockIdx.x - BBLK + PROJ_A, t, xls, wls,
              x, Wtg, a_src, a_dst, h_u16, attn_s4, attn_d4);
}

// K5: within-bucket finish, single global read. Bucket segment -> LDS,
// LDS hist+scan+sort, coalesced 4 B rec write + offsets.
__global__ __launch_bounds__(256) void k_bfinish(
    const uint2* __restrict__ brec64, const int* __restrict__ bbase,
    const int* __restrict__ btotal,
    unsigned* __restrict__ rec, int* __restrict__ offsets)
{
    __shared__ uint2 stage[BCAP];                  // 16 KB
    __shared__ unsigned sorted[BCAP];              // 8 KB
    __shared__ int bin[32], bcur[32];
    const int j = blockIdx.x;
    const int t = threadIdx.x;
    const int start = bbase[j];
    const int n = btotal[j];

    if (t < 32) bin[t] = 0;
    __syncthreads();
    for (int i = t; i < n; i += 256) {
        const uint2 v = brec64[start + i];
        stage[i] = v;
        atomicAdd(&bin[v.y], 1);
    }
    __syncthreads();
    if (t == 0) {
        int run = 0;
        #pragma unroll
        for (int b = 0; b < 32; ++b) { bcur[b] = run; run += bin[b]; }
    }
    __syncthreads();
    if (t < 32) {
        const int d = j * 32 + t;
        if (d < N_NODES) offsets[d] = start + bcur[t];
    }
    __syncthreads();
    for (int i = t; i < n; i += 256) {
        const uint2 v = stage[i];
        sorted[atomicAdd(&bcur[v.y], 1)] = v.x;
    }
    __syncthreads();
    for (int i = t; i < n; i += 256) rec[start + i] = sorted[i];
}

// K6: per-dst gather-aggregate. DECOUPLED p-phase: h-gathers issue off the
// raw rec broadcast (src bits) BEFORE the exp chain completes; p broadcast
// separately as f16. den = per-lane partial + one 16-lane reduce per dst.
__global__ __launch_bounds__(256) void k_aggregate(
    const unsigned* __restrict__ rec, const int* __restrict__ offsets,
    const float* __restrict__ attn_s4, const float* __restrict__ attn_d4,
    const unsigned* __restrict__ h32, float* __restrict__ out)
{
    const int l = threadIdx.x & 63;
    const int le = l & 15;                         // edge slot
    const int lh = l >> 4;                         // head
    const int wid = blockIdx.x * 4 + (threadIdx.x >> 6);
    const unsigned* hp = h32 + l;

    for (int dst = wid; dst < N_NODES; dst += AGG_WAVES) {
        const int beg = offsets[dst];
        const int end = offsets[dst + 1];
        const float ad = attn_d4[dst * HEADS + lh];
        float dacc = 0.f;
        float a0 = 0.f, a1 = 0.f, b0 = 0.f, b1 = 0.f;
        for (int c = beg; c < end; c += 16) {
            const int cnt = min(16, end - c);
            unsigned u = 0;
            float pr = 0.f;
            if (le < cnt) {
                u = rec[c + le];
                const int s = u >> 16;
                float lo = attn_s4[s * HEADS + lh] + ad;
                lo = ((lo >= 0.f) ? lo : NEG_SLOPE * lo) * f16u(u & 0xffffu);
                pr = __expf(lo);
            }
            const unsigned pk = (unsigned)f16_bits(pr);
            dacc += f16u((unsigned short)pk);
            if (cnt == 16) {
                // h-gathers depend only on u (src) -> issue before exp done
                unsigned hv[16];
                #pragma unroll
                for (int q = 0; q < 16; ++q) {
                    const unsigned uq = (unsigned)__shfl((int)u, q, 16);
                    hv[q] = hp[(size_t)(uq >> 16) * 64];
                }
                #pragma unroll
                for (int q = 0; q < 16; q += 2) {
                    const float p0 = f16u((unsigned short)__shfl((int)pk, q, 16));
                    const float p1 = f16u((unsigned short)__shfl((int)pk, q + 1, 16));
                    a0 = fmaf(p0, __uint_as_float(hv[q] << 16), a0);
                    b0 = fmaf(p0, __uint_as_float(hv[q] & 0xffff0000u), b0);
                    a1 = fmaf(p1, __uint_as_float(hv[q + 1] << 16), a1);
                    b1 = fmaf(p1, __uint_as_float(hv[q + 1] & 0xffff0000u), b1);
                }
            } else {
                for (int q = 0; q < cnt; ++q) {
                    const unsigned uq = (unsigned)__shfl((int)u, q, 16);
                    const float p0 = f16u((unsigned short)__shfl((int)pk, q, 16));
                    const unsigned h0 = hp[(size_t)(uq >> 16) * 64];
                    a0 = fmaf(p0, __uint_as_float(h0 << 16), a0);
                    b0 = fmaf(p0, __uint_as_float(h0 & 0xffff0000u), b0);
                }
            }
        }
        float den = dacc;
        #pragma unroll
        for (int m = 8; m >= 1; m >>= 1) den += __shfl_xor(den, m, 16);
        const float inv = 1.f / (den + 1e-10f);
        float2 o;
        o.x = (a0 + a1) * inv;
        o.y = (b0 + b1) * inv;
        ((float2*)out)[(size_t)dst * 64 + l] = o;
    }
}

extern "C" void kernel_launch(void* const* d_in, const int* in_sizes, int n_in,
                              void* d_out, int out_size, void* d_ws, size_t ws_size,
                              hipStream_t stream) {
    const float* x   = (const float*)d_in[0];
    const int*   ei  = (const int*)d_in[1];
    const float* ew  = (const float*)d_in[2];
    const float* W   = (const float*)d_in[3];
    const float* a_s = (const float*)d_in[4];
    const float* a_d = (const float*)d_in[5];
    float* out = (float*)d_out;

    unsigned* h32     = (unsigned*)d_ws;                          // 12.8 MB
    float*    attn_s4 = (float*)(h32 + (size_t)N_NODES * 64);     // 800 KB
    float*    attn_d4 = attn_s4 + (size_t)N_NODES * HEADS;        // 800 KB
    uint2*    brec64  = (uint2*)(attn_d4 + (size_t)N_NODES * HEADS); // 12.8 MB
    unsigned* rec     = (unsigned*)(brec64 + N_EDGES);            // 6.4 MB
    int*      bhist   = (int*)(rec + N_EDGES);                    // 1.6 MB
    int*      btotal  = bhist + BBLK * NBUCKET;                   // 6.3 KB
    int*      bbase   = btotal + NBUCKET;                         // 6.3 KB
    int*      offsets = bbase + NBUCKET;                          // 200 KB
    unsigned short* Wtg = (unsigned short*)(offsets + N_NODES + 1); // 35 KB

    k_bhist<<<BBLK + 8, 1024, 0, stream>>>(ei, bhist, W, Wtg);
    k_projA_scan<<<SCAN_BLKS + PROJ_A, 256, 0, stream>>>(
        x, Wtg, a_s, a_d, (unsigned short*)h32, attn_s4, attn_d4,
        bhist, btotal);
    k_bbase<<<1, 256, 0, stream>>>(btotal, bbase, offsets);
    k_projB_scatter<<<BBLK + PROJ_B, 256, 0, stream>>>(
        x, Wtg, a_s, a_d, (unsigned short*)h32, attn_s4, attn_d4,
        ei, ew, bhist, bbase, brec64);
    k_bfinish<<<NBUCKET, 256, 0, stream>>>(brec64, bbase, btotal, rec, offsets);
    k_aggregate<<<AGG_BLOCKS, 256, 0, stream>>>(rec, offsets, attn_s4,
                                                attn_d4, h32, out);
}